// Round 11
// baseline (234.996 us; speedup 1.0000x reference)
//
#include <hip/hip_runtime.h>
#include <hip/hip_bf16.h>

typedef __hip_bfloat16 hbf16;

#define Hdim 1024
#define NHEAD 16
#define HDIM 64
#define BATCH 2
#define LQ 1024
#define LK 2048
#define LN_EPS 1e-5f
#define LOG2E 1.4426950408889634f

typedef __bf16 bfv8 __attribute__((ext_vector_type(8)));
typedef float floatx4 __attribute__((ext_vector_type(4)));
typedef union { bfv8 v; __bf16 b[8]; unsigned short s[8]; } bfu8;

#define BK 32
#define LDS_PITCH 40   // 64-wide bf16 rows padded to 80B
#define QT 64
#define KT 64
#define KS_PITCH 72
#define VT_OFF(d) ((d) * 72 + (((d) >> 3) << 3))
#define PS_OFF(r) ((r) * 72 + (((r) >> 2) << 3))

__device__ inline bfv8 cvt2(const float4 x, const float4 y) {
    bfv8 r = {(__bf16)x.x, (__bf16)x.y, (__bf16)x.z, (__bf16)x.w,
              (__bf16)y.x, (__bf16)y.y, (__bf16)y.z, (__bf16)y.w};
    return r;
}

// async global->LDS, 16B per lane (wave-uniform LDS base + lane*16)
__device__ __forceinline__ void glds16(const void* g, void* l) {
    __builtin_amdgcn_global_load_lds(
        (const __attribute__((address_space(1))) void*)g,
        (__attribute__((address_space(3))) void*)l, 16, 0, 0);
}

// ===========================================================================
// one-shot fp32 -> bf16 convert of q,k,v,Wq,Wk,Wv (blocks 0..6655) PLUS
// mask -> fragment-ordered 16-bit pack (blocks 6656..7679), coalesced via
// LDS transpose (R9-proven).
// mpack[( (b*16+qb)*32 + kt )*256 + tid] : bit j=ns*4+rr set iff mask!=0.
// ===========================================================================
__global__ __launch_bounds__(256) void cvt_all(
    const float* __restrict__ q, const float* __restrict__ k,
    const float* __restrict__ v, const float* __restrict__ Wq,
    const float* __restrict__ Wk, const float* __restrict__ Wv,
    const int* __restrict__ mask,
    hbf16* __restrict__ qb, hbf16* __restrict__ kb, hbf16* __restrict__ vb,
    hbf16* __restrict__ Wqb, hbf16* __restrict__ Wkb, hbf16* __restrict__ Wvb,
    unsigned short* __restrict__ mpack) {
    __shared__ int mlds[64][68];   // pitch 68: 16B-aligned int4, ~2-way reads
    const int blk = blockIdx.x;
    if (blk >= 6656) {
        // mask pack path (coalesced)
        const int t = blk - 6656;          // 0..1023
        const int kt = t & 31;
        const int qb2 = (t >> 5) & 15;
        const int b2 = t >> 9;
        const int tid = threadIdx.x;
        {   // coalesced load: thread -> row tid>>2, 16 contiguous ints
            const int r = tid >> 2;
            const int c = (tid & 3) * 16;
            const int4* s4 = (const int4*)(mask +
                (size_t)(b2 * LQ + qb2 * 64 + r) * LK + kt * 64 + c);
            const int4 v0 = s4[0], v1 = s4[1], v2 = s4[2], v3 = s4[3];
            *(int4*)&mlds[r][c] = v0;
            *(int4*)&mlds[r][c + 4] = v1;
            *(int4*)&mlds[r][c + 8] = v2;
            *(int4*)&mlds[r][c + 12] = v3;
        }
        __syncthreads();
        const int w = tid >> 6;
        const int lane = tid & 63;
        const int quad = lane >> 4;
        const int u = lane & 15;
        unsigned int bits = 0;
#pragma unroll
        for (int ns = 0; ns < 4; ++ns)
#pragma unroll
            for (int rr = 0; rr < 4; ++rr)
                if (mlds[w * 16 + quad * 4 + rr][ns * 16 + u] != 0)
                    bits |= 1u << (ns * 4 + rr);
        mpack[(size_t)t * 256 + tid] = (unsigned short)bits;
        return;
    }
    const float* src; hbf16* dst; int base;
    if (blk < 1024)      { src = q;  dst = qb;  base = blk; }
    else if (blk < 3072) { src = k;  dst = kb;  base = blk - 1024; }
    else if (blk < 5120) { src = v;  dst = vb;  base = blk - 3072; }
    else if (blk < 5632) { src = Wq; dst = Wqb; base = blk - 5120; }
    else if (blk < 6144) { src = Wk; dst = Wkb; base = blk - 5632; }
    else                 { src = Wv; dst = Wvb; base = blk - 6144; }
    const size_t e = (size_t)base * 2048 + (size_t)threadIdx.x * 8;
    const float4 a = *(const float4*)(src + e);
    const float4 b = *(const float4*)(src + e + 4);
    *(bfv8*)((__bf16*)dst + e) = cvt2(a, b);
}

// ===========================================================================
// TIER-A projection (R10-proven): glds 2-phase body + 1D XCD-chunked grid
// (640 blocks = 8 XCDs x 80). z selects {Q,K,V}.
// R11: Q pre-scaled by (1/8)*log2e so attention softmax uses bare exp2.
// ===========================================================================
__global__ __launch_bounds__(256) void proj3_glds(
    const hbf16* __restrict__ qb, const hbf16* __restrict__ kb,
    const hbf16* __restrict__ vb,
    const hbf16* __restrict__ Wqb, const hbf16* __restrict__ Wkb,
    const hbf16* __restrict__ Wvb,
    const float* __restrict__ bq, const float* __restrict__ bk,
    const float* __restrict__ bv,
    hbf16* __restrict__ Qp, hbf16* __restrict__ Kp, hbf16* __restrict__ Vp) {
    // bijective XCD swizzle: 640 = 8 x 80, chunk-contiguous per XCD.
    const int wg = (blockIdx.x & 7) * 80 + (blockIdx.x >> 3);
    int z, x, y;
    if (wg < 128)      { z = 0; x = wg & 7; y = wg >> 3; }
    else if (wg < 384) { z = 1; x = (wg - 128) & 7; y = (wg - 128) >> 3; }
    else               { z = 2; x = (wg - 384) & 7; y = (wg - 384) >> 3; }
    const hbf16* A; const hbf16* W; const float* bias; hbf16* out; float scale;
    if (z == 0)      { A = qb; W = Wqb; bias = bq; out = Qp; scale = 0.125f * LOG2E; }
    else if (z == 1) { A = kb; W = Wkb; bias = bk; out = Kp; scale = 1.0f; }
    else             { A = vb; W = Wvb; bias = bv; out = Vp; scale = 1.0f; }

    __shared__ __align__(16) __bf16 As[2][128 * 32];
    __shared__ __align__(16) __bf16 Bs[2][128 * 32];
    const int tid = threadIdx.x;
    const int lane = tid & 63;
    const int w = tid >> 6;
    const int wm = w & 1, wn = w >> 1;
    const int u = lane & 15;
    const int quad = lane >> 4;
    const int rowBase = y * 128;
    const int colBase = x * 128;

    const int srow = tid >> 2;        // 0..63
    const int scol = (tid & 3) * 8;   // bf16 elems
    const hbf16* aP = A + (size_t)(rowBase + srow) * Hdim + scol;
    const hbf16* wP = W + (size_t)(colBase + srow) * Hdim + scol;
    const int ldsOff = srow * 32 + scol;

#define P_STAGE(buf, k0)                                            \
    do {                                                            \
        glds16(aP + (k0), &As[buf][ldsOff]);                        \
        glds16(aP + (k0) + (size_t)64 * Hdim, &As[buf][ldsOff + 64 * 32]); \
        glds16(wP + (k0), &Bs[buf][ldsOff]);                        \
        glds16(wP + (k0) + (size_t)64 * Hdim, &Bs[buf][ldsOff + 64 * 32]); \
    } while (0)

    floatx4 acc[4][4];
#pragma unroll
    for (int mi = 0; mi < 4; ++mi)
#pragma unroll
        for (int ni = 0; ni < 4; ++ni) acc[mi][ni] = (floatx4){0.f, 0.f, 0.f, 0.f};

#define P_COMPUTE(buf)                                                         \
    do {                                                                       \
        bfv8 af[4], bf[4];                                                     \
        _Pragma("unroll") for (int mi = 0; mi < 4; ++mi)                       \
            af[mi] = *(const bfv8*)&As[buf][(wm * 64 + mi * 16 + u) * 32 + quad * 8]; \
        _Pragma("unroll") for (int ni = 0; ni < 4; ++ni)                       \
            bf[ni] = *(const bfv8*)&Bs[buf][(wn * 64 + ni * 16 + u) * 32 + quad * 8]; \
        _Pragma("unroll") for (int mi = 0; mi < 4; ++mi)                       \
            _Pragma("unroll") for (int ni = 0; ni < 4; ++ni)                   \
                acc[mi][ni] = __builtin_amdgcn_mfma_f32_16x16x32_bf16(af[mi], bf[ni], acc[mi][ni], 0, 0, 0); \
    } while (0)

    P_STAGE(0, 0);
    __syncthreads();   // vmcnt(0) drain + barrier: buf0 ready

    for (int t = 0; t < 32; t += 2) {
        if (t + 1 < 32) P_STAGE(1, (t + 1) * 32);
        P_COMPUTE(0);
        __syncthreads();   // prefetch overlapped compute; buf1 ready, buf0 free
        if (t + 2 < 32) P_STAGE(0, (t + 2) * 32);
        P_COMPUTE(1);
        __syncthreads();
    }
#undef P_STAGE
#undef P_COMPUTE

#pragma unroll
    for (int mi = 0; mi < 4; ++mi)
#pragma unroll
        for (int ni = 0; ni < 4; ++ni) {
            const int n = colBase + wn * 64 + ni * 16 + u;
            const float bn = bias[n];
#pragma unroll
            for (int rr = 0; rr < 4; ++rr) {
                const int m = rowBase + wm * 64 + mi * 16 + quad * 4 + rr;
                out[(size_t)m * Hdim + n] = __float2bfloat16((acc[mi][ni][rr] + bn) * scale);
            }
        }
}

// ===========================================================================
// TIER-A fused merge + ctx GEMM (R6-proven): 64x64 tile, 2-phase dbuf.
// A = (Opart0 + Opart1) * 1/(l0+l1) -> bf16, reg-staged issue-early/write-late.
// B = Wo fp32 reg-staged convert. Epilogue: fp32 out = acc + bias + resid.
// ===========================================================================
__global__ __launch_bounds__(256) void gemm_ctx_merge(
    const float* __restrict__ Opart, const float* __restrict__ lpart,
    const float* __restrict__ W, const float* __restrict__ bias,
    const float* __restrict__ resid, float* __restrict__ out) {
    __shared__ __align__(16) __bf16 As[2][64 * 32];
    __shared__ __align__(16) __bf16 Bs[2][64 * 32];
    const int tid = threadIdx.x;
    const int lane = tid & 63;
    const int w = tid >> 6;
    const int wm = w & 1, wn = w >> 1;
    const int u = lane & 15;
    const int quad = lane >> 4;
    const int rowBase = blockIdx.y * 64;
    const int colBase = blockIdx.x * 64;

    const int srow = tid >> 2;          // 0..63
    const int scol = (tid & 3) * 8;     // 0,8,16,24
    const size_t mrow = (size_t)(rowBase + srow);
    const float* o0 = Opart + mrow * Hdim + scol;
    const float* o1 = o0 + (size_t)BATCH * LQ * Hdim;
    const float* lp0 = lpart + mrow * NHEAD;
    const float* lp1 = lp0 + BATCH * LQ * NHEAD;
    const float* wP = W + (size_t)(colBase + srow) * Hdim + scol;
    const int ldsOff = srow * 32 + scol;

    floatx4 acc[2][2];
#pragma unroll
    for (int mi = 0; mi < 2; ++mi)
#pragma unroll
        for (int ni = 0; ni < 2; ++ni) acc[mi][ni] = (floatx4){0.f, 0.f, 0.f, 0.f};

#define C_COMPUTE(buf)                                                         \
    do {                                                                       \
        bfv8 af[2], bf[2];                                                     \
        _Pragma("unroll") for (int mi = 0; mi < 2; ++mi)                       \
            af[mi] = *(const bfv8*)&As[buf][(wm * 32 + mi * 16 + u) * 32 + quad * 8]; \
        _Pragma("unroll") for (int ni = 0; ni < 2; ++ni)                       \
            bf[ni] = *(const bfv8*)&Bs[buf][(wn * 32 + ni * 16 + u) * 32 + quad * 8]; \
        _Pragma("unroll") for (int mi = 0; mi < 2; ++mi)                       \
            _Pragma("unroll") for (int ni = 0; ni < 2; ++ni)                   \
                acc[mi][ni] = __builtin_amdgcn_mfma_f32_16x16x32_bf16(af[mi], bf[ni], acc[mi][ni], 0, 0, 0); \
    } while (0)

#define M_WRITEA(buf, a0, a1, c0, c1, l0v, l1v)                                \
    do {                                                                       \
        const float invl_ = 1.0f / ((l0v) + (l1v));                            \
        float4 s0_, s1_;                                                       \
        s0_.x = (a0.x + c0.x) * invl_; s0_.y = (a0.y + c0.y) * invl_;          \
        s0_.z = (a0.z + c0.z) * invl_; s0_.w = (a0.w + c0.w) * invl_;          \
        s1_.x = (a1.x + c1.x) * invl_; s1_.y = (a1.y + c1.y) * invl_;          \
        s1_.z = (a1.z + c1.z) * invl_; s1_.w = (a1.w + c1.w) * invl_;          \
        *(bfv8*)&As[buf][ldsOff] = cvt2(s0_, s1_);                             \
    } while (0)

    // prologue: stage k-step 0 into buf 0
    {
        const float4 a0 = *(const float4*)(o0);
        const float4 a1 = *(const float4*)(o0 + 4);
        const float4 c0 = *(const float4*)(o1);
        const float4 c1 = *(const float4*)(o1 + 4);
        const int hh = scol >> 6;   // == 0
        const float l0v = lp0[hh], l1v = lp1[hh];
        const float4* w4 = (const float4*)wP;
        const float4 w0 = w4[0], w1 = w4[1];
        M_WRITEA(0, a0, a1, c0, c1, l0v, l1v);
        *(bfv8*)&Bs[0][ldsOff] = cvt2(w0, w1);
    }
    __syncthreads();

    for (int t = 0; t < 32; t += 2) {
        {   // phase 0: compute buf0 (step t), stage t+1 into buf1
            float4 a0, a1, c0, c1, w0, w1; float l0v = 1.f, l1v = 0.f;
            const bool pf = (t + 1 < 32);
            if (pf) {
                const int kk = (t + 1) * 32;
                a0 = *(const float4*)(o0 + kk);
                a1 = *(const float4*)(o0 + kk + 4);
                c0 = *(const float4*)(o1 + kk);
                c1 = *(const float4*)(o1 + kk + 4);
                const int hh = (kk + scol) >> 6;
                l0v = lp0[hh]; l1v = lp1[hh];
                const float4* w4 = (const float4*)(wP + kk);
                w0 = w4[0]; w1 = w4[1];
            }
            C_COMPUTE(0);
            if (pf) {   // write-late: global-load waits sink below MFMAs
                M_WRITEA(1, a0, a1, c0, c1, l0v, l1v);
                *(bfv8*)&Bs[1][ldsOff] = cvt2(w0, w1);
            }
            __syncthreads();
        }
        {   // phase 1: compute buf1 (step t+1), stage t+2 into buf0
            float4 a0, a1, c0, c1, w0, w1; float l0v = 1.f, l1v = 0.f;
            const bool pf = (t + 2 < 32);
            if (pf) {
                const int kk = (t + 2) * 32;
                a0 = *(const float4*)(o0 + kk);
                a1 = *(const float4*)(o0 + kk + 4);
                c0 = *(const float4*)(o1 + kk);
                c1 = *(const float4*)(o1 + kk + 4);
                const int hh = (kk + scol) >> 6;
                l0v = lp0[hh]; l1v = lp1[hh];
                const float4* w4 = (const float4*)(wP + kk);
                w0 = w4[0]; w1 = w4[1];
            }
            C_COMPUTE(1);
            if (pf) {
                M_WRITEA(0, a0, a1, c0, c1, l0v, l1v);
                *(bfv8*)&Bs[0][ldsOff] = cvt2(w0, w1);
            }
            __syncthreads();
        }
    }
#undef C_COMPUTE
#undef M_WRITEA

#pragma unroll
    for (int mi = 0; mi < 2; ++mi)
#pragma unroll
        for (int ni = 0; ni < 2; ++ni) {
            const int n = colBase + wn * 32 + ni * 16 + u;
            const float bn = bias[n];
#pragma unroll
            for (int rr = 0; rr < 4; ++rr) {
                const int m = rowBase + wm * 32 + mi * 16 + quad * 4 + rr;
                out[(size_t)m * Hdim + n] = acc[mi][ni][rr] + bn + resid[(size_t)m * Hdim + n];
            }
        }
}

// ===========================================================================
// TIER-B fused Q/K/V projection (one launch, z selects input). 64x64, BK=32.
// ===========================================================================
__global__ __launch_bounds__(256) void proj3_mfma(
    const float* __restrict__ q_in, const float* __restrict__ k_in,
    const float* __restrict__ v_in,
    const float* __restrict__ Wq, const float* __restrict__ bq,
    const float* __restrict__ Wk, const float* __restrict__ bk,
    const float* __restrict__ Wv, const float* __restrict__ bv,
    hbf16* __restrict__ Qp, hbf16* __restrict__ Kp, hbf16* __restrict__ Vp) {
    const int z = blockIdx.z;
    if (z == 0 && blockIdx.y >= (BATCH * LQ) / 64) return;
    const float* A; const float* W; const float* bias; hbf16* out; float scale;
    if (z == 0)      { A = q_in; W = Wq; bias = bq; out = Qp; scale = 0.125f; }
    else if (z == 1) { A = k_in; W = Wk; bias = bk; out = Kp; scale = 1.0f; }
    else             { A = v_in; W = Wv; bias = bv; out = Vp; scale = 1.0f; }

    __shared__ __align__(16) __bf16 As[64 * LDS_PITCH];
    __shared__ __align__(16) __bf16 Bs[64 * LDS_PITCH];
    const int tid = threadIdx.x;
    const int lane = tid & 63;
    const int w = tid >> 6;
    const int wm = w & 1, wn = w >> 1;
    const int rowBase = blockIdx.y * 64;
    const int colBase = blockIdx.x * 64;
    const int sr = tid >> 2;
    const int scg = (tid & 3) * 8;
    const int lr = lane & 15;
    const int quad = lane >> 4;

    floatx4 acc[2][2] = {};

    for (int k0 = 0; k0 < Hdim; k0 += BK) {
        const float* ap = A + (size_t)(rowBase + sr) * Hdim + k0 + scg;
        bfv8 av = cvt2(((const float4*)ap)[0], ((const float4*)ap)[1]);
        const float* wp = W + (size_t)(colBase + sr) * Hdim + k0 + scg;
        bfv8 bv8 = cvt2(((const float4*)wp)[0], ((const float4*)wp)[1]);
        __syncthreads();
        *(bfv8*)&As[sr * LDS_PITCH + scg] = av;
        *(bfv8*)&Bs[sr * LDS_PITCH + scg] = bv8;
        __syncthreads();

        bfv8 bf[2];
#pragma unroll
        for (int nt = 0; nt < 2; ++nt)
            bf[nt] = *(const bfv8*)&Bs[(wn * 32 + nt * 16 + lr) * LDS_PITCH + quad * 8];
#pragma unroll
        for (int mt = 0; mt < 2; ++mt) {
            bfv8 af = *(const bfv8*)&As[(wm * 32 + mt * 16 + lr) * LDS_PITCH + quad * 8];
#pragma unroll
            for (int nt = 0; nt < 2; ++nt)
                acc[mt][nt] = __builtin_amdgcn_mfma_f32_16x16x32_bf16(af, bf[nt], acc[mt][nt], 0, 0, 0);
        }
    }

#pragma unroll
    for (int mt = 0; mt < 2; ++mt)
#pragma unroll
        for (int nt = 0; nt < 2; ++nt) {
            const int n = colBase + wn * 32 + nt * 16 + lr;
            const float bn = bias[n];
#pragma unroll
            for (int rr = 0; rr < 4; ++rr) {
                const int m = rowBase + wm * 32 + mt * 16 + quad * 4 + rr;
                out[(size_t)m * Hdim + n] = __float2bfloat16((acc[mt][nt][rr] + bn) * scale);
            }
        }
}

// ===========================================================================
// TIER-B GEMM (R10 path): 64x64, fp32 in, bf16 out, scale.
// ===========================================================================
__global__ __launch_bounds__(256) void gemm_mfma_f32(const float* __restrict__ A,
                                                     const float* __restrict__ W,
                                                     const float* __restrict__ bias,
                                                     hbf16* __restrict__ out,
                                                     float scale) {
    __shared__ __align__(16) __bf16 As[64 * LDS_PITCH];
    __shared__ __align__(16) __bf16 Bs[64 * LDS_PITCH];
    const int tid = threadIdx.x;
    const int lane = tid & 63;
    const int w = tid >> 6;
    const int wm = w & 1, wn = w >> 1;
    const int rowBase = blockIdx.y * 64;
    const int colBase = blockIdx.x * 64;
    const int sr = tid >> 2;
    const int scg = (tid & 3) * 8;
    const int lr = lane & 15;
    const int quad = lane >> 4;

    floatx4 acc[2][2] = {};

    for (int k0 = 0; k0 < Hdim; k0 += BK) {
        const float* ap = A + (size_t)(rowBase + sr) * Hdim + k0 + scg;
        bfv8 av = cvt2(((const float4*)ap)[0], ((const float4*)ap)[1]);
        const float* wp = W + (size_t)(colBase + sr) * Hdim + k0 + scg;
        bfv8 bv = cvt2(((const float4*)wp)[0], ((const float4*)wp)[1]);
        __syncthreads();
        *(bfv8*)&As[sr * LDS_PITCH + scg] = av;
        *(bfv8*)&Bs[sr * LDS_PITCH + scg] = bv;
        __syncthreads();

        bfv8 bf[2];
#pragma unroll
        for (int nt = 0; nt < 2; ++nt)
            bf[nt] = *(const bfv8*)&Bs[(wn * 32 + nt * 16 + lr) * LDS_PITCH + quad * 8];
#pragma unroll
        for (int mt = 0; mt < 2; ++mt) {
            bfv8 af = *(const bfv8*)&As[(wm * 32 + mt * 16 + lr) * LDS_PITCH + quad * 8];
#pragma unroll
            for (int nt = 0; nt < 2; ++nt)
                acc[mt][nt] = __builtin_amdgcn_mfma_f32_16x16x32_bf16(af, bf[nt], acc[mt][nt], 0, 0, 0);
        }
    }

#pragma unroll
    for (int mt = 0; mt < 2; ++mt)
#pragma unroll
        for (int nt = 0; nt < 2; ++nt) {
            const int n = colBase + wn * 32 + nt * 16 + lr;
            const float bn = bias[n];
#pragma unroll
            for (int rr = 0; rr < 4; ++rr) {
                const int m = rowBase + wm * 32 + mt * 16 + quad * 4 + rr;
                out[(size_t)m * Hdim + n] = __float2bfloat16((acc[mt][nt][rr] + bn) * scale);
            }
        }
}

// ===========================================================================
// ctx GEMM (TIER-B): bf16 A + fp32 W + residual -> fp32 out.
// ===========================================================================
__global__ __launch_bounds__(256) void gemm_mfma_ctx(const hbf16* __restrict__ A,
                                                     const float* __restrict__ W,
                                                     const float* __restrict__ bias,
                                                     const float* __restrict__ resid,
                                                     float* __restrict__ out) {
    __shared__ __align__(16) __bf16 As[64 * LDS_PITCH];
    __shared__ __align__(16) __bf16 Bs[64 * LDS_PITCH];
    const int tid = threadIdx.x;
    const int lane = tid & 63;
    const int w = tid >> 6;
    const int wm = w & 1, wn = w >> 1;
    const int rowBase = blockIdx.y * 64;
    const int colBase = blockIdx.x * 64;
    const int sr = tid >> 2;
    const int scg = (tid & 3) * 8;
    const int lr = lane & 15;
    const int quad = lane >> 4;

    floatx4 acc[2][2] = {};

    for (int k0 = 0; k0 < Hdim; k0 += BK) {
        bfv8 av = *(const bfv8*)(A + (size_t)(rowBase + sr) * Hdim + k0 + scg);
        const float* wp = W + (size_t)(colBase + sr) * Hdim + k0 + scg;
        bfv8 bv = cvt2(((const float4*)wp)[0], ((const float4*)wp)[1]);
        __syncthreads();
        *(bfv8*)&As[sr * LDS_PITCH + scg] = av;
        *(bfv8*)&Bs[sr * LDS_PITCH + scg] = bv;
        __syncthreads();

        bfv8 bf[2];
#pragma unroll
        for (int nt = 0; nt < 2; ++nt)
            bf[nt] = *(const bfv8*)&Bs[(wn * 32 + nt * 16 + lr) * LDS_PITCH + quad * 8];
#pragma unroll
        for (int mt = 0; mt < 2; ++mt) {
            bfv8 af = *(const bfv8*)&As[(wm * 32 + mt * 16 + lr) * LDS_PITCH + quad * 8];
#pragma unroll
            for (int nt = 0; nt < 2; ++nt)
                acc[mt][nt] = __builtin_amdgcn_mfma_f32_16x16x32_bf16(af, bf[nt], acc[mt][nt], 0, 0, 0);
        }
    }

#pragma unroll
    for (int mt = 0; mt < 2; ++mt)
#pragma unroll
        for (int nt = 0; nt < 2; ++nt) {
            const int n = colBase + wn * 32 + nt * 16 + lr;
            const float bn = bias[n];
#pragma unroll
            for (int rr = 0; rr < 4; ++rr) {
                const int m = rowBase + wm * 32 + mt * 16 + quad * 4 + rr;
                out[(size_t)m * Hdim + n] = acc[mt][nt][rr] + bn + resid[(size_t)m * Hdim + n];
            }
        }
}

// ===========================================================================
// mask prep (TIER-B only): int32 mask -> fragment-ordered bf16 bias.
// ===========================================================================
__global__ __launch_bounds__(256) void mask_prep_st(const int* __restrict__ mask,
                                                    hbf16* __restrict__ mbias) {
    const int t = blockIdx.x;          // 0..1023
    const int kt = t & 31;
    const int qb = (t >> 5) & 15;
    const int b = t >> 9;
    const int tid = threadIdx.x;
    const int w = tid >> 6;
    const int lane = tid & 63;
    const int quad = lane >> 4;
    const int u = lane & 15;
    const int qrow = qb * 64 + w * 16 + quad * 4;
    const int kcol = kt * 64 + u;
    const int* mp = mask + ((size_t)(b * LQ + qrow)) * LK + kcol;

    bfu8 v0, v1;
#pragma unroll
    for (int ns = 0; ns < 4; ++ns)
#pragma unroll
        for (int rr = 0; rr < 4; ++rr) {
            const int mv = mp[(size_t)rr * LK + ns * 16];
            const __bf16 bias = (mv == 0) ? (__bf16)(-1e9f) : (__bf16)(-10.0f);
            const int j = ns * 4 + rr;
            if (j < 8) v0.b[j] = bias; else v1.b[j - 8] = bias;
        }
    __bf16* dst = (__bf16*)mbias + (size_t)t * 4096 + tid * 16;
    *(bfv8*)dst = v0.v;
    *(bfv8*)(dst + 8) = v1.v;
}

// ===========================================================================
// TIER-A: split-K=2 flash attention, static softmax, UNNORMALIZED partials.
// R11: Q pre-scaled by log2e in proj -> softmax is bare exp2 (no v_mul per
// element). Bias constants folded: -10*log2e / -1e9*log2e. Mask via packed
// u16, XCD swizzle, T14 prefetch, setprio (all R10-proven).
// ===========================================================================
__global__ __launch_bounds__(256, 4) void attn_split(const hbf16* __restrict__ Qp,
                                                     const hbf16* __restrict__ Kp,
                                                     const hbf16* __restrict__ Vp,
                                                     const unsigned short* __restrict__ mpack,
                                                     float* __restrict__ Opart,
                                                     float* __restrict__ lpart) {
    // bijective XCD swizzle: 1024 blocks = 8 XCDs x 128-chunk; qb fastest.
    const int wg = (blockIdx.x & 7) * 128 + (blockIdx.x >> 3);
    const int qb = wg & 15;
    const int h = (wg >> 4) & 15;
    const int z = wg >> 8;
    const int b = z >> 1;
    const int sp = z & 1;
    const int tid = threadIdx.x;
    const int lane = tid & 63;
    const int w = tid >> 6;
    const int u = lane & 15;
    const int quad = lane >> 4;
    const int qBase = qb * QT;

    __shared__ __align__(16) __bf16 Ks[64 * KS_PITCH];
    __shared__ __align__(16) __bf16 Vt[4672];
    __shared__ __align__(16) __bf16 Ps[4][1184];

    const int qrow_frag = qBase + w * 16 + u;
    const hbf16* qptr = Qp + (size_t)(b * LQ + qrow_frag) * Hdim + h * HDIM + quad * 8;
    const bfv8 af_q0 = *(const bfv8*)qptr;
    const bfv8 af_q1 = *(const bfv8*)(qptr + 32);

    float l_acc[4] = {0.f, 0.f, 0.f, 0.f};
    floatx4 acc_o[4];
#pragma unroll
    for (int nd = 0; nd < 4; ++nd) acc_o[nd] = (floatx4){0.f, 0.f, 0.f, 0.f};

    const int sk = tid >> 2;
    const int sdg = (tid & 3) * 16;
    const int vk2 = (tid >> 3) * 2;
    const int vd0 = (tid & 7) * 8;
    // packed mask: one u16 per thread per tile, fragment-ordered
    const unsigned short* mpk = mpack + (size_t)((b * 16 + qb) * 32) * 256 + tid;

    const int kt0 = sp * (LK / KT / 2);
    const int ktEnd = kt0 + (LK / KT / 2);

    // bias constants pre-multiplied by log2e (S is already scaled by log2e)
    const float BIAS_KEEP = -10.0f * LOG2E;
    const float BIAS_MASK = -1e9f * LOG2E;

    // pending-tile registers (T14 issue-early)
    unsigned int pmw;
    bfu8 pv0, pv1;
    bfv8 pk0, pk1;

#define A_LOADS(kt)                                                            \
    do {                                                                       \
        const int kBase_ = (kt) * KT;                                          \
        pmw = mpk[(size_t)(kt) * 256];                                         \
        const hbf16* vp_ = Vp + (size_t)(b * LK + kBase_ + vk2) * Hdim + h * HDIM + vd0; \
        pv0.v = *(const bfv8*)vp_;                                             \
        pv1.v = *(const bfv8*)(vp_ + Hdim);                                    \
        const hbf16* kp_ = Kp + (size_t)(b * LK + kBase_ + sk) * Hdim + h * HDIM + sdg; \
        pk0 = *(const bfv8*)kp_;                                               \
        pk1 = *(const bfv8*)(kp_ + 8);                                         \
    } while (0)

    A_LOADS(kt0);

    for (int kt = kt0; kt < ktEnd; ++kt) {
        __syncthreads();   // all waves done reading LDS of previous tile
        *(bfv8*)&Ks[sk * KS_PITCH + sdg] = pk0;
        *(bfv8*)&Ks[sk * KS_PITCH + sdg + 8] = pk1;
#pragma unroll
        for (int i = 0; i < 8; ++i) {
            unsigned int pk = (unsigned int)pv0.s[i] | ((unsigned int)pv1.s[i] << 16);
            *(unsigned int*)&Vt[VT_OFF(vd0 + i) + vk2] = pk;
        }
        const unsigned int mw = pmw;   // snapshot current-tile mask word
        __syncthreads();               // LDS tile ready

        // issue next-tile loads NOW; latency hides under QK+softmax+PV
        if (kt + 1 < ktEnd) A_LOADS(kt + 1);

        // S = Q K^T (Q pre-scaled (1/8)*log2e)
        floatx4 acc_s[4];
        __builtin_amdgcn_s_setprio(1);
#pragma unroll
        for (int ns = 0; ns < 4; ++ns) {
            const bfv8 bk0 = *(const bfv8*)&Ks[(ns * 16 + u) * KS_PITCH + quad * 8];
            const bfv8 bk1 = *(const bfv8*)&Ks[(ns * 16 + u) * KS_PITCH + quad * 8 + 32];
            floatx4 a = (floatx4){0.f, 0.f, 0.f, 0.f};
            a = __builtin_amdgcn_mfma_f32_16x16x32_bf16(af_q0, bk0, a, 0, 0, 0);
            a = __builtin_amdgcn_mfma_f32_16x16x32_bf16(af_q1, bk1, a, 0, 0, 0);
            acc_s[ns] = a;
        }
        __builtin_amdgcn_s_setprio(0);

        // static softmax: p = 2^(s + bias2) (bare v_exp, no per-elem mul)
        __bf16* Pw = Ps[w];
#pragma unroll
        for (int ns = 0; ns < 4; ++ns)
#pragma unroll
            for (int rr = 0; rr < 4; ++rr) {
                const int j = ns * 4 + rr;
                const float bias = ((mw >> j) & 1u) ? BIAS_KEEP : BIAS_MASK;
                const float p = exp2f(acc_s[ns][rr] + bias);
                Pw[PS_OFF(quad * 4 + rr) + ns * 16 + u] = (__bf16)p;
                l_acc[rr] += p;
            }

        // O += P V (same-wave LDS RAW ordered by lgkmcnt)
        const bfv8 af_p0 = *(const bfv8*)&Pw[PS_OFF(u) + quad * 8];
        const bfv8 af_p1 = *(const bfv8*)&Pw[PS_OFF(u) + quad * 8 + 32];
        __builtin_amdgcn_s_setprio(1);
#pragma unroll
        for (int nd = 0; nd < 4; ++nd) {
            const bfv8 bv0 = *(const bfv8*)&Vt[VT_OFF(nd * 16 + u) + quad * 8];
            const bfv8 bv1 = *(const bfv8*)&Vt[VT_OFF(nd * 16 + u) + quad * 8 + 32];
            acc_o[nd] = __builtin_amdgcn_mfma_f32_16x16x32_bf16(af_p0, bv0, acc_o[nd], 0, 0, 0);
            acc_o[nd] = __builtin_amdgcn_mfma_f32_16x16x32_bf16(af_p1, bv1, acc_o[nd], 0, 0, 0);
        }
        __builtin_amdgcn_s_setprio(0);
    }
#undef A_LOADS

    // epilogue: unnormalized O + l partials
#pragma unroll
    for (int rr = 0; rr < 4; ++rr) {
        float l = l_acc[rr];
        l += __shfl_xor(l, 1, 64);
        l += __shfl_xor(l, 2, 64);
        l += __shfl_xor(l, 4, 64);
        l += __shfl_xor(l, 8, 64);
        const int qrow = qBase + w * 16 + quad * 4 + rr;
        const size_t m = (size_t)(b * LQ + qrow);
        float* orow = Opart + (size_t)sp * (BATCH * LQ * Hdim) + m * Hdim + h * HDIM;
#pragma unroll
        for (int nd = 0; nd < 4; ++nd)
            orow[nd * 16 + u] = acc_o[nd][rr];
        if (u == 0)
            lpart[(size_t)sp * (BATCH * LQ * NHEAD) + m * NHEAD + h] = l;
    }
}

// ===========================================================================
// TIER-B attention (R10 proven): single-block-per-(qtile,h,b) static softmax.
// ===========================================================================
__global__ __launch_bounds__(256, 4) void attn_flash_st(const hbf16* __restrict__ Qp,
                                                        const hbf16* __restrict__ Kp,
                                                        const hbf16* __restrict__ Vp,
                                                        const hbf16* __restrict__ mbias,
                                                        hbf16* __restrict__ ctx) {
    const int qb = blockIdx.x;
    const int h = blockIdx.y;
    const int b = blockIdx.z;
    const int tid = threadIdx.x;
    const int lane = tid & 63;
    const int w = tid >> 6;
    const int u = lane & 15;
    const int quad = lane >> 4;
    const int qBase = qb * QT;

    __shared__ __align__(16) __bf16 Ks[64 * KS_PITCH];
    __shared__ __align__(16) __bf16 Vt[4672];
    __shared__ __align__(16) __bf16 Ps[4][1184];

    const int qrow_frag = qBase + w * 16 + u;
    const hbf16* qptr = Qp + (size_t)(b * LQ + qrow_frag) * Hdim + h * HDIM + quad * 8;
    const bfv8 af_q0 = *(const bfv8*)qptr;
    const bfv8 af_q1 = *(const bfv8*)(qptr + 32);

    float l_acc[4] = {0.f, 0.f, 0.f, 0.f};
    floatx4 acc_o[4];
#pragma unroll
    for (int nd = 0; nd < 4; ++nd) acc_o[nd] = (floatx4){0.f, 0.f, 0.f, 0.f};

    const int sk = tid >> 2;
    const int sdg = (tid & 3) * 16;
    const int vk2 = (tid >> 3) * 2;
    const int vd0 = (tid & 7) * 8;
    const __bf16* mbT = (const __bf16*)mbias + (size_t)(b * 16 + qb) * 32 * 4096 + tid * 16;

    for (int kt = 0; kt < LK / KT; ++kt) {
        const int kBase = kt * KT;

        bfu8 mb0, mb1;
        mb0.v = *(const bfv8*)(mbT + (size_t)kt * 4096);
        mb1.v = *(const bfv8*)(mbT + (size_t)kt * 4096 + 8);

        const hbf16* vp0 = Vp + (size_t)(b * LK + kBase + vk2) * Hdim + h * HDIM + vd0;
        bfu8 v0, v1;
        v0.v = *(const bfv8*)vp0;
        v1.v = *(const bfv8*)(vp0 + Hdim);
        const hbf16* kp = Kp + (size_t)(b * LK + kBase + sk) * Hdim + h * HDIM + sdg;
        const bfv8 kv0 = *(const bfv8*)kp;
        const bfv8 kv1 = *(const bfv8*)(kp + 8);

        __syncthreads();
        *(bfv8*)&Ks[sk * KS_PITCH + sdg] = kv0;
        *(bfv8*)&Ks[sk * KS_PITCH + sdg + 8] = kv1;
#pragma unroll
        for (int i = 0; i < 8; ++i) {
            unsigned int pk = (unsigned int)v0.s[i] | ((unsigned int)v1.s[i] << 16);
            *(unsigned int*)&Vt[VT_OFF(vd0 + i) + vk2] = pk;
        }
        __syncthreads();

        floatx4 acc_s[4];
#pragma unroll
        for (int ns = 0; ns < 4; ++ns) {
            const bfv8 bk0 = *(const bfv8*)&Ks[(ns * 16 + u) * KS_PITCH + quad * 8];
            const bfv8 bk1 = *(const bfv8*)&Ks[(ns * 16 + u) * KS_PITCH + quad * 8 + 32];
            floatx4 a = (floatx4){0.f, 0.f, 0.f, 0.f};
            a = __builtin_amdgcn_mfma_f32_16x16x32_bf16(af_q0, bk0, a, 0, 0, 0);
            a = __builtin_amdgcn_mfma_f32_16x16x32_bf16(af_q1, bk1, a, 0, 0, 0);
            acc_s[ns] = a;
        }

        __bf16* Pw = Ps[w];
#pragma unroll
        for (int ns = 0; ns < 4; ++ns)
#pragma unroll
            for (int rr = 0; rr < 4; ++rr) {
                const int j = ns * 4 + rr;
                const float bias = (j < 8) ? (float)mb0.b[j] : (float)mb1.b[j - 8];
                const float p = __expf(acc_s[ns][rr] + bias);
                Pw[PS_OFF(quad * 4 + rr) + ns * 16 + u] = (__bf16)p;
                l_acc[rr] += p;
            }

        const bfv8 af_p0 = *(const bfv8*)&Pw[PS_OFF(u) + quad * 8];
        const bfv8 af_p1 = *(const bfv8*)&Pw[PS_OFF(u) + quad * 8 + 32];
#pragma unroll
        for (int nd = 0; nd < 4; ++nd) {
            const bfv8 bv0 = *(const bfv8*)&Vt[VT_OFF(nd * 16 + u) + quad * 8];
            const bfv8 bv1 = *(const bfv8*)&Vt[VT_OFF(nd * 16 + u) + quad * 8 + 32];
            acc_o[nd] = __builtin_amdgcn_mfma_f32_16x16x32_bf16(af_p0, bv0, acc_o[nd], 0, 0, 0);
            acc_o[nd] = __builtin_amdgcn_mfma_f32_16x16x32_bf16(af_p1, bv1, acc_o[nd], 0, 0, 0);
        }
    }

#pragma unroll
    for (int rr = 0; rr < 4; ++rr) {
        float l = l_acc[rr];
        l += __shfl_xor(l, 1, 64);
        l += __shfl_xor(l, 2, 64);
        l += __shfl_xor(l, 4, 64);
        l += __shfl_xor(l, 8, 64);
        const float invl = 1.0f / l;
        const int qrow = qBase + w * 16 + quad * 4 + rr;
        hbf16* crow = ctx + (size_t)(b * LQ + qrow) * Hdim + h * HDIM;
#pragma unroll
        for (int nd = 0; nd < 4; ++nd)
            crow[nd * 16 + u] = __float2bfloat16(acc_o[nd][rr] * invl);
    }
}

// ===========================================================================
// LayerNorm over last dim (1024), fp32 in d_out, in place.
// ===========================================================================
__global__ __launch_bounds__(256) void ln_kernel(float* __restrict__ x,
                                                 const float* __restrict__ g,
                                                 const float* __restrict__ beta) {
    const int row = blockIdx.x;
    float* xr = x + (size_t)row * Hdim;
    __shared__ float red[256];
    const int tid = threadIdx.x;

    const float4 xi = ((const float4*)xr)[tid];
    red[tid] = xi.x + xi.y + xi.z + xi.w;
    __syncthreads();
    for (int st = 128; st > 0; st >>= 1) {
        if (tid < st) red[tid] += red[tid + st];
        __syncthreads();
    }
    const float mu = red[0] * (1.0f / Hdim);
    __syncthreads();
    {
        float dx = xi.x - mu, dy = xi.y - mu, dz = xi.z - mu, dw = xi.w - mu;
        red[tid] = dx * dx + dy * dy + dz * dz + dw * dw;
    }
    __syncthreads();
    for (int st = 128; st > 0; st >>= 1) {
        if (tid < st) red[tid] += red[tid + st];
        __syncthreads();
    }
    const float rstd = rsqrtf(red[0] * (1.0f / Hdim) + LN_EPS);

    const float4 g4 = ((const float4*)g)[tid];
    const float4 b4 = ((const float4*)beta)[tid];
    float4 y;
    y.x = (xi.x - mu) * rstd * g4.x + b4.x;
    y.y = (xi.y - mu) * rstd * g4.y + b4.y;
    y.z = (xi.z - mu) * rstd * g4.z + b4.z;
    y.w = (xi.w - mu) * rstd * g4.w + b4.w;
    ((float4*)xr)[tid] = y;
}

// ===========================================================================
// Fallback (round-4 proven): fully fused, zero workspace.
// ===========================================================================
__device__ inline float wave_red_sum(float v) {
    v += __shfl_down(v, 32, 64);
    v += __shfl_down(v, 16, 64);
    v += __shfl_down(v, 8, 64);
    v += __shfl_down(v, 4, 64);
    v += __shfl_down(v, 2, 64);
    v += __shfl_down(v, 1, 64);
    return v;
}

__global__ __launch_bounds__(256) void fused_mha(
    const float* __restrict__ q_in, const float* __restrict__ k_in,
    const float* __restrict__ v_in, const int* __restrict__ mask,
    const float* __restrict__ Wq, const float* __restrict__ bq,
    const float* __restrict__ Wk, const float* __restrict__ bk,
    const float* __restrict__ Wv, const float* __restrict__ bv,
    const float* __restrict__ Wo, const float* __restrict__ bo,
    const float* __restrict__ ln_g, const float* __restrict__ ln_b,
    float* __restrict__ out) {
    const int q = blockIdx.x;
    const int b = blockIdx.y;
    const int tid = threadIdx.x;
    const int lane = tid & 63;
    const int w = tid >> 6;

    __shared__ float qrow[Hdim];
    __shared__ float qt[Hdim];
    __shared__ float sc[LK];
    __shared__ float u[Hdim];
    __shared__ float ctxv[Hdim];
    __shared__ float Qh[HDIM];
    __shared__ float red[256];
    __shared__ float sb_sh;

    const float* qp = q_in + (size_t)(b * LQ + q) * Hdim;
    for (int i = tid; i < Hdim; i += 256) qrow[i] = qp[i];
    __syncthreads();

    const float* keyb = k_in + (size_t)b * LK * Hdim;
    const float* valb = v_in + (size_t)b * LK * Hdim;
    const int* mrow = mask + (size_t)(b * LQ + q) * LK;

    for (int h = 0; h < NHEAD; ++h) {
        for (int dd = w; dd < HDIM; dd += 4) {
            const float4* wrow = (const float4*)(Wq + (size_t)(h * HDIM + dd) * Hdim);
            const float4* q4 = (const float4*)qrow;
            float p = 0.f;
#pragma unroll
            for (int i0 = 0; i0 < 4; ++i0) {
                float4 a = wrow[i0 * 64 + lane];
                float4 c = q4[i0 * 64 + lane];
                p += a.x * c.x + a.y * c.y + a.z * c.z + a.w * c.w;
            }
            p = wave_red_sum(p);
            if (lane == 0) Qh[dd] = p + bq[h * HDIM + dd];
        }
        __syncthreads();

        if (tid < HDIM) red[tid] = Qh[tid] * bk[h * HDIM + tid];

        float4 s4 = {0.f, 0.f, 0.f, 0.f};
        for (int d = 0; d < HDIM; ++d) {
            float4 a = ((const float4*)(Wk + (size_t)(h * HDIM + d) * Hdim))[tid];
            float qd = Qh[d];
            s4.x += a.x * qd;
            s4.y += a.y * qd;
            s4.z += a.z * qd;
            s4.w += a.w * qd;
        }
        __syncthreads();
        if (tid == 0) {
            float s = 0.f;
            for (int i = 0; i < HDIM; ++i) s += red[i];
            sb_sh = s;
        }
        ((float4*)qt)[tid] = s4;
        __syncthreads();
        const float sb = sb_sh;

        for (int k = w; k < LK; k += 4) {
            const float4* krow = (const float4*)(keyb + (size_t)k * Hdim);
            const float4* q4 = (const float4*)qt;
            float p = 0.f;
#pragma unroll
            for (int i0 = 0; i0 < 4; ++i0) {
                float4 a = krow[i0 * 64 + lane];
                float4 c = q4[i0 * 64 + lane];
                p += a.x * c.x + a.y * c.y + a.z * c.z + a.w * c.w;
            }
            p = wave_red_sum(p);
            if (lane == 0) {
                float s = (p + sb) * 0.125f;
                if (mrow[k] == 0) s = -1e9f;
                sc[k] = s;
            }
        }
        __syncthreads();

        float m = -1e30f;
        for (int k = tid; k < LK; k += 256) m = fmaxf(m, sc[k]);
        red[tid] = m;
        __syncthreads();
        for (int s = 128; s > 0; s >>= 1) {
            if (tid < s) red[tid] = fmaxf(red[tid], red[tid + s]);
            __syncthreads();
        }
        const float mx = red[0];
        __syncthreads();
        float sum = 0.f;
        for (int k = tid; k < LK; k += 256) {
            float e = __expf(sc[k] - mx);
            sc[k] = e;
            sum += e;
        }
        red[tid] = sum;
        __syncthreads();
        for (int s = 128; s > 0; s >>= 1) {
            if (tid < s) red[tid] += red[tid + s];
            __syncthreads();
        }
        const float inv = 1.0f / red[0];
        for (int k = tid; k < LK; k += 256) sc[k] *= inv;
        __syncthreads();

        {
            float4 acc = {0.f, 0.f, 0.f, 0.f};
            const float4* vb4 = (const float4*)valb;
#pragma unroll 4
            for (int k = 0; k < LK; ++k) {
                float p = sc[k];
                float4 a = vb4[(size_t)k * (Hdim / 4) + tid];
                acc.x += a.x * p;
                acc.y += a.y * p;
                acc.z += a.z * p;
                acc.w += a.w * p;
            }
            ((float4*)u)[tid] = acc;
        }
        __syncthreads();

        for (int dd = w; dd < HDIM; dd += 4) {
            const float4* wrow = (const float4*)(Wv + (size_t)(h * HDIM + dd) * Hdim);
            const float4* u4 = (const float4*)u;
            float p = 0.f;
#pragma unroll
            for (int i0 = 0; i0 < 4; ++i0) {
                float4 a = wrow[i0 * 64 + lane];
                float4 c = u4[i0 * 64 + lane];
                p += a.x * c.x + a.y * c.y + a.z * c.z + a.w * c.w;
            }
            p = wave_red_sum(p);
            if (lane == 0) ctxv[h * HDIM + dd] = p + bv[h * HDIM + dd];
        }
        __syncthreads();
    }

    for (int n = w; n < Hdim; n += 4) {
        const float4* wrow = (const float4*)(Wo + (size_t)n * Hdim);
        const float4* c4 = (const float4*)ctxv;
        float p = 0.f;
#pragma unroll
        for (int i0 = 0; i0 < 4; ++i0) {
            float4 a = wrow[i0 * 64 + lane];
            float4 c = c4[i0 * 64 + lane];
            p += a.x * c.x + a.y * c.y + a.z * c.z + a.w * c.w;
        }
        p = wave_red_sum(p);
        if (lane == 0) qt[n] = p + bo[n] + qrow[n];
    }
    __syncthreads();

    {
        const float4 x4 = ((const float4*)qt)[tid];
        red[tid] = x4.x + x4.y + x4.z + x4.w;
    }
    __syncthreads();
    for (int s = 128; s > 0; s >>= 1) {
        if (tid < s) red[tid] += red[tid + s];
        __syncthreads();
    }
    const float mu = red[0] * (1.0f / Hdim);
    __syncthreads();
    {
        const float4 x4 = ((const float4*)qt)[tid];
        float dx = x4.x - mu, dy = x4.y - mu, dz = x4.z - mu, dw = x4.w - mu;
        red[tid] = dx * dx + dy * dy + dz * dz + dw * dw;
    }
    __syncthreads();
    for (int s = 128; s > 0; s >>= 1) {
        if (tid < s) red[tid] += red[tid + s];
        __syncthreads();
    }
    const float rstd = rsqrtf(red[0] * (1.0f / Hdim) + LN_EPS);

    float* orow = out + (size_t)(b * LQ + q) * Hdim;
    const float4 x4 = ((const float4*)qt)[tid];
    const float4 g4 = ((const float4*)ln_g)[tid];
    const float4 b4 = ((const float4*)ln_b)[tid];
    float4 y;
    y.x = (x4.x - mu) * rstd * g4.x + b4.x;
    y.y = (x4.y - mu) * rstd * g4.y + b4.y;
    y.z = (x4.z - mu) * rstd * g4.z + b4.z;
    y.w = (x4.w - mu) * rstd * g4.w + b4.w;
    ((float4*)orow)[tid] = y;
}

extern "C" void kernel_launch(void* const* d_in, const int* in_sizes, int n_in,
                              void* d_out, int out_size, void* d_ws, size_t ws_size,
                              hipStream_t stream) {
    const float* query = (const float*)d_in[0];
    const float* key   = (const float*)d_in[1];
    const float* value = (const float*)d_in[2];
    const int*   mask  = (const int*)d_in[3];
    const float* Wq = (const float*)d_in[4];
    const float* bq = (const float*)d_in[5];
    const float* Wk = (const float*)d_in[6];
    const float* bk = (const float*)d_in[7];
    const float* Wv = (const float*)d_in[8];
    const float* bv = (const float*)d_in[9];
    const float* Wo = (const float*)d_in[10];
    const float* bo = (const float*)d_in[11];
    const float* ln_g = (const float*)d_in[12];
    const float* ln_b = (const float*)d_in[13];
    float* out = (float*)d_out;

    const size_t MB = 1024 * 1024;
    dim3 blk(256);

    if (ws_size >= 50 * MB) {
        // TIER-A (5 kernels): cvt+maskpack -> proj(1D XCD grid) -> attn(exp2)
        //                     -> merge+ctxGEMM -> ln
        // Persistent: Qp@0(4) Kp@4(8) Vp@12(8) Opart@20(16) mpack@46(1) lpart@47(1)
        // cvt scratch (dead before Opart written; disjoint from mpack):
        //   qb@20(4) kb@24(8) vb@32(8) Wqb@40(2) Wkb@42(2) Wvb@44(2)  -> 20..46
        char* p = (char*)d_ws;
        hbf16* Qp    = (hbf16*)(p + 0 * MB);
        hbf16* Kp    = (hbf16*)(p + 4 * MB);
        hbf16* Vp    = (hbf16*)(p + 12 * MB);
        float* Opart = (float*)(p + 20 * MB);
        unsigned short* mpack = (unsigned short*)(p + 46 * MB);
        float* lpart = (float*)(p + 47 * MB);

        hbf16* qb  = (hbf16*)(p + 20 * MB);
        hbf16* kb  = (hbf16*)(p + 24 * MB);
        hbf16* vb  = (hbf16*)(p + 32 * MB);
        hbf16* Wqb = (hbf16*)(p + 40 * MB);
        hbf16* Wkb = (hbf16*)(p + 42 * MB);
        hbf16* Wvb = (hbf16*)(p + 44 * MB);

        cvt_all<<<dim3(7680), blk, 0, stream>>>(query, key, value, Wq, Wk, Wv,
                                                mask, qb, kb, vb, Wqb, Wkb, Wvb,
                                                mpack);
        proj3_glds<<<dim3(640), blk, 0, stream>>>(
            qb, kb, vb, Wqb, Wkb, Wvb, bq, bk, bv, Qp, Kp, Vp);

        attn_split<<<dim3(1024), blk, 0, stream>>>(
            Qp, Kp, Vp, mpack, Opart, lpart);

        gemm_ctx_merge<<<dim3(Hdim / 64, (BATCH * LQ) / 64), blk, 0, stream>>>(
            Opart, lpart, Wo, bo, query, out);
        ln_kernel<<<BATCH * LQ, blk, 0, stream>>>(out, ln_g, ln_b);
    } else if (ws_size >= 32 * MB) {
        // TIER-B: exact round-10 proven path
        char* p = (char*)d_ws;
        hbf16* Qp = (hbf16*)p;    p += 4 * MB;
        hbf16* Kp = (hbf16*)p;    p += 8 * MB;
        hbf16* Vp = (hbf16*)p;    p += 8 * MB;
        hbf16* ctxb = (hbf16*)p;  p += 4 * MB;
        hbf16* mbias = (hbf16*)p; p += 8 * MB;

        gemm_mfma_f32<<<dim3(Hdim / 64, (BATCH * LQ) / 64), blk, 0, stream>>>(query, Wq, bq, Qp, 0.125f);
        gemm_mfma_f32<<<dim3(Hdim / 64, (BATCH * LK) / 64), blk, 0, stream>>>(key, Wk, bk, Kp, 1.0f);
        gemm_mfma_f32<<<dim3(Hdim / 64, (BATCH * LK) / 64), blk, 0, stream>>>(value, Wv, bv, Vp, 1.0f);
        mask_prep_st<<<dim3(1024), blk, 0, stream>>>(mask, mbias);
        attn_flash_st<<<dim3(LQ / QT, NHEAD, BATCH), blk, 0, stream>>>(Qp, Kp, Vp, mbias, ctxb);
        gemm_mfma_ctx<<<dim3(Hdim / 64, (BATCH * LQ) / 64), blk, 0, stream>>>(ctxb, Wo, bo, query, out);
        ln_kernel<<<BATCH * LQ, blk, 0, stream>>>(out, ln_g, ln_b);
    } else {
        fused_mha<<<dim3(LQ, BATCH), dim3(256), 0, stream>>>(
            query, key, value, mask, Wq, bq, Wk, bk, Wv, bv, Wo, bo, ln_g, ln_b, out);
    }
}

// Round 13
// 228.684 us; speedup vs baseline: 1.0276x; 1.0276x over previous
//
#include <hip/hip_runtime.h>
#include <hip/hip_bf16.h>

typedef __hip_bfloat16 hbf16;

#define Hdim 1024
#define NHEAD 16
#define HDIM 64
#define BATCH 2
#define LQ 1024
#define LK 2048
#define LN_EPS 1e-5f
#define LOG2E 1.4426950408889634f

typedef __bf16 bfv8 __attribute__((ext_vector_type(8)));
typedef float floatx4 __attribute__((ext_vector_type(4)));
typedef union { bfv8 v; __bf16 b[8]; unsigned short s[8]; } bfu8;

#define BK 32
#define LDS_PITCH 40   // 64-wide bf16 rows padded to 80B
#define QT 64
#define KT 64
#define KS_PITCH 72
#define VT_OFF(d) ((d) * 72 + (((d) >> 3) << 3))
#define PS_OFF(r) ((r) * 72 + (((r) >> 2) << 3))

__device__ inline bfv8 cvt2(const float4 x, const float4 y) {
    bfv8 r = {(__bf16)x.x, (__bf16)x.y, (__bf16)x.z, (__bf16)x.w,
              (__bf16)y.x, (__bf16)y.y, (__bf16)y.z, (__bf16)y.w};
    return r;
}

// async global->LDS, 16B per lane (wave-uniform LDS base + lane*16)
__device__ __forceinline__ void glds16(const void* g, void* l) {
    __builtin_amdgcn_global_load_lds(
        (const __attribute__((address_space(1))) void*)g,
        (__attribute__((address_space(3))) void*)l, 16, 0, 0);
}

// ===========================================================================
// one-shot fp32 -> bf16 convert of q,k,v,Wq,Wk,Wv (blocks 0..6655) PLUS
// mask -> fragment-ordered 16-bit pack (blocks 6656..7679), coalesced via
// LDS transpose (R9-proven).
// mpack[( (b*16+qb)*32 + kt )*256 + tid] : bit j=ns*4+rr set iff mask!=0.
// ===========================================================================
__global__ __launch_bounds__(256) void cvt_all(
    const float* __restrict__ q, const float* __restrict__ k,
    const float* __restrict__ v, const float* __restrict__ Wq,
    const float* __restrict__ Wk, const float* __restrict__ Wv,
    const int* __restrict__ mask,
    hbf16* __restrict__ qb, hbf16* __restrict__ kb, hbf16* __restrict__ vb,
    hbf16* __restrict__ Wqb, hbf16* __restrict__ Wkb, hbf16* __restrict__ Wvb,
    unsigned short* __restrict__ mpack) {
    __shared__ int mlds[64][68];   // pitch 68: 16B-aligned int4, ~2-way reads
    const int blk = blockIdx.x;
    if (blk >= 6656) {
        // mask pack path (coalesced)
        const int t = blk - 6656;          // 0..1023
        const int kt = t & 31;
        const int qb2 = (t >> 5) & 15;
        const int b2 = t >> 9;
        const int tid = threadIdx.x;
        {   // coalesced load: thread -> row tid>>2, 16 contiguous ints
            const int r = tid >> 2;
            const int c = (tid & 3) * 16;
            const int4* s4 = (const int4*)(mask +
                (size_t)(b2 * LQ + qb2 * 64 + r) * LK + kt * 64 + c);
            const int4 v0 = s4[0], v1 = s4[1], v2 = s4[2], v3 = s4[3];
            *(int4*)&mlds[r][c] = v0;
            *(int4*)&mlds[r][c + 4] = v1;
            *(int4*)&mlds[r][c + 8] = v2;
            *(int4*)&mlds[r][c + 12] = v3;
        }
        __syncthreads();
        const int w = tid >> 6;
        const int lane = tid & 63;
        const int quad = lane >> 4;
        const int u = lane & 15;
        unsigned int bits = 0;
#pragma unroll
        for (int ns = 0; ns < 4; ++ns)
#pragma unroll
            for (int rr = 0; rr < 4; ++rr)
                if (mlds[w * 16 + quad * 4 + rr][ns * 16 + u] != 0)
                    bits |= 1u << (ns * 4 + rr);
        mpack[(size_t)t * 256 + tid] = (unsigned short)bits;
        return;
    }
    const float* src; hbf16* dst; int base;
    if (blk < 1024)      { src = q;  dst = qb;  base = blk; }
    else if (blk < 3072) { src = k;  dst = kb;  base = blk - 1024; }
    else if (blk < 5120) { src = v;  dst = vb;  base = blk - 3072; }
    else if (blk < 5632) { src = Wq; dst = Wqb; base = blk - 5120; }
    else if (blk < 6144) { src = Wk; dst = Wkb; base = blk - 5632; }
    else                 { src = Wv; dst = Wvb; base = blk - 6144; }
    const size_t e = (size_t)base * 2048 + (size_t)threadIdx.x * 8;
    const float4 a = *(const float4*)(src + e);
    const float4 b = *(const float4*)(src + e + 4);
    *(bfv8*)((__bf16*)dst + e) = cvt2(a, b);
}

// ===========================================================================
// TIER-A projection (R10-proven): glds 2-phase body + 1D XCD-chunked grid
// (640 blocks = 8 XCDs x 80). z selects {Q,K,V}.
// Q pre-scaled by (1/8)*log2e so attention softmax uses bare exp2 (R11-proven).
// ===========================================================================
__global__ __launch_bounds__(256) void proj3_glds(
    const hbf16* __restrict__ qb, const hbf16* __restrict__ kb,
    const hbf16* __restrict__ vb,
    const hbf16* __restrict__ Wqb, const hbf16* __restrict__ Wkb,
    const hbf16* __restrict__ Wvb,
    const float* __restrict__ bq, const float* __restrict__ bk,
    const float* __restrict__ bv,
    hbf16* __restrict__ Qp, hbf16* __restrict__ Kp, hbf16* __restrict__ Vp) {
    // bijective XCD swizzle: 640 = 8 x 80, chunk-contiguous per XCD.
    const int wg = (blockIdx.x & 7) * 80 + (blockIdx.x >> 3);
    int z, x, y;
    if (wg < 128)      { z = 0; x = wg & 7; y = wg >> 3; }
    else if (wg < 384) { z = 1; x = (wg - 128) & 7; y = (wg - 128) >> 3; }
    else               { z = 2; x = (wg - 384) & 7; y = (wg - 384) >> 3; }
    const hbf16* A; const hbf16* W; const float* bias; hbf16* out; float scale;
    if (z == 0)      { A = qb; W = Wqb; bias = bq; out = Qp; scale = 0.125f * LOG2E; }
    else if (z == 1) { A = kb; W = Wkb; bias = bk; out = Kp; scale = 1.0f; }
    else             { A = vb; W = Wvb; bias = bv; out = Vp; scale = 1.0f; }

    __shared__ __align__(16) __bf16 As[2][128 * 32];
    __shared__ __align__(16) __bf16 Bs[2][128 * 32];
    const int tid = threadIdx.x;
    const int lane = tid & 63;
    const int w = tid >> 6;
    const int wm = w & 1, wn = w >> 1;
    const int u = lane & 15;
    const int quad = lane >> 4;
    const int rowBase = y * 128;
    const int colBase = x * 128;

    const int srow = tid >> 2;        // 0..63
    const int scol = (tid & 3) * 8;   // bf16 elems
    const hbf16* aP = A + (size_t)(rowBase + srow) * Hdim + scol;
    const hbf16* wP = W + (size_t)(colBase + srow) * Hdim + scol;
    const int ldsOff = srow * 32 + scol;

#define P_STAGE(buf, k0)                                            \
    do {                                                            \
        glds16(aP + (k0), &As[buf][ldsOff]);                        \
        glds16(aP + (k0) + (size_t)64 * Hdim, &As[buf][ldsOff + 64 * 32]); \
        glds16(wP + (k0), &Bs[buf][ldsOff]);                        \
        glds16(wP + (k0) + (size_t)64 * Hdim, &Bs[buf][ldsOff + 64 * 32]); \
    } while (0)

    floatx4 acc[4][4];
#pragma unroll
    for (int mi = 0; mi < 4; ++mi)
#pragma unroll
        for (int ni = 0; ni < 4; ++ni) acc[mi][ni] = (floatx4){0.f, 0.f, 0.f, 0.f};

#define P_COMPUTE(buf)                                                         \
    do {                                                                       \
        bfv8 af[4], bf[4];                                                     \
        _Pragma("unroll") for (int mi = 0; mi < 4; ++mi)                       \
            af[mi] = *(const bfv8*)&As[buf][(wm * 64 + mi * 16 + u) * 32 + quad * 8]; \
        _Pragma("unroll") for (int ni = 0; ni < 4; ++ni)                       \
            bf[ni] = *(const bfv8*)&Bs[buf][(wn * 64 + ni * 16 + u) * 32 + quad * 8]; \
        _Pragma("unroll") for (int mi = 0; mi < 4; ++mi)                       \
            _Pragma("unroll") for (int ni = 0; ni < 4; ++ni)                   \
                acc[mi][ni] = __builtin_amdgcn_mfma_f32_16x16x32_bf16(af[mi], bf[ni], acc[mi][ni], 0, 0, 0); \
    } while (0)

    P_STAGE(0, 0);
    __syncthreads();   // vmcnt(0) drain + barrier: buf0 ready

    for (int t = 0; t < 32; t += 2) {
        if (t + 1 < 32) P_STAGE(1, (t + 1) * 32);
        P_COMPUTE(0);
        __syncthreads();   // prefetch overlapped compute; buf1 ready, buf0 free
        if (t + 2 < 32) P_STAGE(0, (t + 2) * 32);
        P_COMPUTE(1);
        __syncthreads();
    }
#undef P_STAGE
#undef P_COMPUTE

#pragma unroll
    for (int mi = 0; mi < 4; ++mi)
#pragma unroll
        for (int ni = 0; ni < 4; ++ni) {
            const int n = colBase + wn * 64 + ni * 16 + u;
            const float bn = bias[n];
#pragma unroll
            for (int rr = 0; rr < 4; ++rr) {
                const int m = rowBase + wm * 64 + mi * 16 + quad * 4 + rr;
                out[(size_t)m * Hdim + n] = __float2bfloat16((acc[mi][ni][rr] + bn) * scale);
            }
        }
}

// ===========================================================================
// TIER-A fused merge + ctx GEMM (R6-proven): 64x64 tile, 2-phase dbuf.
// A = (Opart0 + Opart1) * 1/(l0+l1) -> bf16, reg-staged issue-early/write-late.
// B = Wo fp32 reg-staged convert. Epilogue: fp32 out = acc + bias + resid.
// ===========================================================================
__global__ __launch_bounds__(256) void gemm_ctx_merge(
    const float* __restrict__ Opart, const float* __restrict__ lpart,
    const float* __restrict__ W, const float* __restrict__ bias,
    const float* __restrict__ resid, float* __restrict__ out) {
    __shared__ __align__(16) __bf16 As[2][64 * 32];
    __shared__ __align__(16) __bf16 Bs[2][64 * 32];
    const int tid = threadIdx.x;
    const int lane = tid & 63;
    const int w = tid >> 6;
    const int wm = w & 1, wn = w >> 1;
    const int u = lane & 15;
    const int quad = lane >> 4;
    const int rowBase = blockIdx.y * 64;
    const int colBase = blockIdx.x * 64;

    const int srow = tid >> 2;          // 0..63
    const int scol = (tid & 3) * 8;     // 0,8,16,24
    const size_t mrow = (size_t)(rowBase + srow);
    const float* o0 = Opart + mrow * Hdim + scol;
    const float* o1 = o0 + (size_t)BATCH * LQ * Hdim;
    const float* lp0 = lpart + mrow * NHEAD;
    const float* lp1 = lp0 + BATCH * LQ * NHEAD;
    const float* wP = W + (size_t)(colBase + srow) * Hdim + scol;
    const int ldsOff = srow * 32 + scol;

    floatx4 acc[2][2];
#pragma unroll
    for (int mi = 0; mi < 2; ++mi)
#pragma unroll
        for (int ni = 0; ni < 2; ++ni) acc[mi][ni] = (floatx4){0.f, 0.f, 0.f, 0.f};

#define C_COMPUTE(buf)                                                         \
    do {                                                                       \
        bfv8 af[2], bf[2];                                                     \
        _Pragma("unroll") for (int mi = 0; mi < 2; ++mi)                       \
            af[mi] = *(const bfv8*)&As[buf][(wm * 32 + mi * 16 + u) * 32 + quad * 8]; \
        _Pragma("unroll") for (int ni = 0; ni < 2; ++ni)                       \
            bf[ni] = *(const bfv8*)&Bs[buf][(wn * 32 + ni * 16 + u) * 32 + quad * 8]; \
        _Pragma("unroll") for (int mi = 0; mi < 2; ++mi)                       \
            _Pragma("unroll") for (int ni = 0; ni < 2; ++ni)                   \
                acc[mi][ni] = __builtin_amdgcn_mfma_f32_16x16x32_bf16(af[mi], bf[ni], acc[mi][ni], 0, 0, 0); \
    } while (0)

#define M_WRITEA(buf, a0, a1, c0, c1, l0v, l1v)                                \
    do {                                                                       \
        const float invl_ = 1.0f / ((l0v) + (l1v));                            \
        float4 s0_, s1_;                                                       \
        s0_.x = (a0.x + c0.x) * invl_; s0_.y = (a0.y + c0.y) * invl_;          \
        s0_.z = (a0.z + c0.z) * invl_; s0_.w = (a0.w + c0.w) * invl_;          \
        s1_.x = (a1.x + c1.x) * invl_; s1_.y = (a1.y + c1.y) * invl_;          \
        s1_.z = (a1.z + c1.z) * invl_; s1_.w = (a1.w + c1.w) * invl_;          \
        *(bfv8*)&As[buf][ldsOff] = cvt2(s0_, s1_);                             \
    } while (0)

    // prologue: stage k-step 0 into buf 0
    {
        const float4 a0 = *(const float4*)(o0);
        const float4 a1 = *(const float4*)(o0 + 4);
        const float4 c0 = *(const float4*)(o1);
        const float4 c1 = *(const float4*)(o1 + 4);
        const int hh = scol >> 6;   // == 0
        const float l0v = lp0[hh], l1v = lp1[hh];
        const float4* w4 = (const float4*)wP;
        const float4 w0 = w4[0], w1 = w4[1];
        M_WRITEA(0, a0, a1, c0, c1, l0v, l1v);
        *(bfv8*)&Bs[0][ldsOff] = cvt2(w0, w1);
    }
    __syncthreads();

    for (int t = 0; t < 32; t += 2) {
        {   // phase 0: compute buf0 (step t), stage t+1 into buf1
            float4 a0, a1, c0, c1, w0, w1; float l0v = 1.f, l1v = 0.f;
            const bool pf = (t + 1 < 32);
            if (pf) {
                const int kk = (t + 1) * 32;
                a0 = *(const float4*)(o0 + kk);
                a1 = *(const float4*)(o0 + kk + 4);
                c0 = *(const float4*)(o1 + kk);
                c1 = *(const float4*)(o1 + kk + 4);
                const int hh = (kk + scol) >> 6;
                l0v = lp0[hh]; l1v = lp1[hh];
                const float4* w4 = (const float4*)(wP + kk);
                w0 = w4[0]; w1 = w4[1];
            }
            C_COMPUTE(0);
            if (pf) {   // write-late: global-load waits sink below MFMAs
                M_WRITEA(1, a0, a1, c0, c1, l0v, l1v);
                *(bfv8*)&Bs[1][ldsOff] = cvt2(w0, w1);
            }
            __syncthreads();
        }
        {   // phase 1: compute buf1 (step t+1), stage t+2 into buf0
            float4 a0, a1, c0, c1, w0, w1; float l0v = 1.f, l1v = 0.f;
            const bool pf = (t + 2 < 32);
            if (pf) {
                const int kk = (t + 2) * 32;
                a0 = *(const float4*)(o0 + kk);
                a1 = *(const float4*)(o0 + kk + 4);
                c0 = *(const float4*)(o1 + kk);
                c1 = *(const float4*)(o1 + kk + 4);
                const int hh = (kk + scol) >> 6;
                l0v = lp0[hh]; l1v = lp1[hh];
                const float4* w4 = (const float4*)(wP + kk);
                w0 = w4[0]; w1 = w4[1];
            }
            C_COMPUTE(1);
            if (pf) {
                M_WRITEA(0, a0, a1, c0, c1, l0v, l1v);
                *(bfv8*)&Bs[0][ldsOff] = cvt2(w0, w1);
            }
            __syncthreads();
        }
    }
#undef C_COMPUTE
#undef M_WRITEA

#pragma unroll
    for (int mi = 0; mi < 2; ++mi)
#pragma unroll
        for (int ni = 0; ni < 2; ++ni) {
            const int n = colBase + wn * 32 + ni * 16 + u;
            const float bn = bias[n];
#pragma unroll
            for (int rr = 0; rr < 4; ++rr) {
                const int m = rowBase + wm * 32 + mi * 16 + quad * 4 + rr;
                out[(size_t)m * Hdim + n] = acc[mi][ni][rr] + bn + resid[(size_t)m * Hdim + n];
            }
        }
}

// ===========================================================================
// TIER-B fused Q/K/V projection (one launch, z selects input). 64x64, BK=32.
// ===========================================================================
__global__ __launch_bounds__(256) void proj3_mfma(
    const float* __restrict__ q_in, const float* __restrict__ k_in,
    const float* __restrict__ v_in,
    const float* __restrict__ Wq, const float* __restrict__ bq,
    const float* __restrict__ Wk, const float* __restrict__ bk,
    const float* __restrict__ Wv, const float* __restrict__ bv,
    hbf16* __restrict__ Qp, hbf16* __restrict__ Kp, hbf16* __restrict__ Vp) {
    const int z = blockIdx.z;
    if (z == 0 && blockIdx.y >= (BATCH * LQ) / 64) return;
    const float* A; const float* W; const float* bias; hbf16* out; float scale;
    if (z == 0)      { A = q_in; W = Wq; bias = bq; out = Qp; scale = 0.125f; }
    else if (z == 1) { A = k_in; W = Wk; bias = bk; out = Kp; scale = 1.0f; }
    else             { A = v_in; W = Wv; bias = bv; out = Vp; scale = 1.0f; }

    __shared__ __align__(16) __bf16 As[64 * LDS_PITCH];
    __shared__ __align__(16) __bf16 Bs[64 * LDS_PITCH];
    const int tid = threadIdx.x;
    const int lane = tid & 63;
    const int w = tid >> 6;
    const int wm = w & 1, wn = w >> 1;
    const int rowBase = blockIdx.y * 64;
    const int colBase = blockIdx.x * 64;
    const int sr = tid >> 2;
    const int scg = (tid & 3) * 8;
    const int lr = lane & 15;
    const int quad = lane >> 4;

    floatx4 acc[2][2] = {};

    for (int k0 = 0; k0 < Hdim; k0 += BK) {
        const float* ap = A + (size_t)(rowBase + sr) * Hdim + k0 + scg;
        bfv8 av = cvt2(((const float4*)ap)[0], ((const float4*)ap)[1]);
        const float* wp = W + (size_t)(colBase + sr) * Hdim + k0 + scg;
        bfv8 bv8 = cvt2(((const float4*)wp)[0], ((const float4*)wp)[1]);
        __syncthreads();
        *(bfv8*)&As[sr * LDS_PITCH + scg] = av;
        *(bfv8*)&Bs[sr * LDS_PITCH + scg] = bv8;
        __syncthreads();

        bfv8 bf[2];
#pragma unroll
        for (int nt = 0; nt < 2; ++nt)
            bf[nt] = *(const bfv8*)&Bs[(wn * 32 + nt * 16 + lr) * LDS_PITCH + quad * 8];
#pragma unroll
        for (int mt = 0; mt < 2; ++mt) {
            bfv8 af = *(const bfv8*)&As[(wm * 32 + mt * 16 + lr) * LDS_PITCH + quad * 8];
#pragma unroll
            for (int nt = 0; nt < 2; ++nt)
                acc[mt][nt] = __builtin_amdgcn_mfma_f32_16x16x32_bf16(af, bf[nt], acc[mt][nt], 0, 0, 0);
        }
    }

#pragma unroll
    for (int mt = 0; mt < 2; ++mt)
#pragma unroll
        for (int nt = 0; nt < 2; ++nt) {
            const int n = colBase + wn * 32 + nt * 16 + lr;
            const float bn = bias[n];
#pragma unroll
            for (int rr = 0; rr < 4; ++rr) {
                const int m = rowBase + wm * 32 + mt * 16 + quad * 4 + rr;
                out[(size_t)m * Hdim + n] = __float2bfloat16((acc[mt][nt][rr] + bn) * scale);
            }
        }
}

// ===========================================================================
// TIER-B GEMM (R10 path): 64x64, fp32 in, bf16 out, scale.
// ===========================================================================
__global__ __launch_bounds__(256) void gemm_mfma_f32(const float* __restrict__ A,
                                                     const float* __restrict__ W,
                                                     const float* __restrict__ bias,
                                                     hbf16* __restrict__ out,
                                                     float scale) {
    __shared__ __align__(16) __bf16 As[64 * LDS_PITCH];
    __shared__ __align__(16) __bf16 Bs[64 * LDS_PITCH];
    const int tid = threadIdx.x;
    const int lane = tid & 63;
    const int w = tid >> 6;
    const int wm = w & 1, wn = w >> 1;
    const int rowBase = blockIdx.y * 64;
    const int colBase = blockIdx.x * 64;
    const int sr = tid >> 2;
    const int scg = (tid & 3) * 8;
    const int lr = lane & 15;
    const int quad = lane >> 4;

    floatx4 acc[2][2] = {};

    for (int k0 = 0; k0 < Hdim; k0 += BK) {
        const float* ap = A + (size_t)(rowBase + sr) * Hdim + k0 + scg;
        bfv8 av = cvt2(((const float4*)ap)[0], ((const float4*)ap)[1]);
        const float* wp = W + (size_t)(colBase + sr) * Hdim + k0 + scg;
        bfv8 bv = cvt2(((const float4*)wp)[0], ((const float4*)wp)[1]);
        __syncthreads();
        *(bfv8*)&As[sr * LDS_PITCH + scg] = av;
        *(bfv8*)&Bs[sr * LDS_PITCH + scg] = bv;
        __syncthreads();

        bfv8 bf[2];
#pragma unroll
        for (int nt = 0; nt < 2; ++nt)
            bf[nt] = *(const bfv8*)&Bs[(wn * 32 + nt * 16 + lr) * LDS_PITCH + quad * 8];
#pragma unroll
        for (int mt = 0; mt < 2; ++mt) {
            bfv8 af = *(const bfv8*)&As[(wm * 32 + mt * 16 + lr) * LDS_PITCH + quad * 8];
#pragma unroll
            for (int nt = 0; nt < 2; ++nt)
                acc[mt][nt] = __builtin_amdgcn_mfma_f32_16x16x32_bf16(af, bf[nt], acc[mt][nt], 0, 0, 0);
        }
    }

#pragma unroll
    for (int mt = 0; mt < 2; ++mt)
#pragma unroll
        for (int nt = 0; nt < 2; ++nt) {
            const int n = colBase + wn * 32 + nt * 16 + lr;
            const float bn = bias[n];
#pragma unroll
            for (int rr = 0; rr < 4; ++rr) {
                const int m = rowBase + wm * 32 + mt * 16 + quad * 4 + rr;
                out[(size_t)m * Hdim + n] = __float2bfloat16((acc[mt][nt][rr] + bn) * scale);
            }
        }
}

// ===========================================================================
// ctx GEMM (TIER-B): bf16 A + fp32 W + residual -> fp32 out.
// ===========================================================================
__global__ __launch_bounds__(256) void gemm_mfma_ctx(const hbf16* __restrict__ A,
                                                     const float* __restrict__ W,
                                                     const float* __restrict__ bias,
                                                     const float* __restrict__ resid,
                                                     float* __restrict__ out) {
    __shared__ __align__(16) __bf16 As[64 * LDS_PITCH];
    __shared__ __align__(16) __bf16 Bs[64 * LDS_PITCH];
    const int tid = threadIdx.x;
    const int lane = tid & 63;
    const int w = tid >> 6;
    const int wm = w & 1, wn = w >> 1;
    const int rowBase = blockIdx.y * 64;
    const int colBase = blockIdx.x * 64;
    const int sr = tid >> 2;
    const int scg = (tid & 3) * 8;
    const int lr = lane & 15;
    const int quad = lane >> 4;

    floatx4 acc[2][2] = {};

    for (int k0 = 0; k0 < Hdim; k0 += BK) {
        bfv8 av = *(const bfv8*)(A + (size_t)(rowBase + sr) * Hdim + k0 + scg);
        const float* wp = W + (size_t)(colBase + sr) * Hdim + k0 + scg;
        bfv8 bv = cvt2(((const float4*)wp)[0], ((const float4*)wp)[1]);
        __syncthreads();
        *(bfv8*)&As[sr * LDS_PITCH + scg] = av;
        *(bfv8*)&Bs[sr * LDS_PITCH + scg] = bv;
        __syncthreads();

        bfv8 bf[2];
#pragma unroll
        for (int nt = 0; nt < 2; ++nt)
            bf[nt] = *(const bfv8*)&Bs[(wn * 32 + nt * 16 + lr) * LDS_PITCH + quad * 8];
#pragma unroll
        for (int mt = 0; mt < 2; ++mt) {
            bfv8 af = *(const bfv8*)&As[(wm * 32 + mt * 16 + lr) * LDS_PITCH + quad * 8];
#pragma unroll
            for (int nt = 0; nt < 2; ++nt)
                acc[mt][nt] = __builtin_amdgcn_mfma_f32_16x16x32_bf16(af, bf[nt], acc[mt][nt], 0, 0, 0);
        }
    }

#pragma unroll
    for (int mt = 0; mt < 2; ++mt)
#pragma unroll
        for (int nt = 0; nt < 2; ++nt) {
            const int n = colBase + wn * 32 + nt * 16 + lr;
            const float bn = bias[n];
#pragma unroll
            for (int rr = 0; rr < 4; ++rr) {
                const int m = rowBase + wm * 32 + mt * 16 + quad * 4 + rr;
                out[(size_t)m * Hdim + n] = acc[mt][nt][rr] + bn + resid[(size_t)m * Hdim + n];
            }
        }
}

// ===========================================================================
// mask prep (TIER-B only): int32 mask -> fragment-ordered bf16 bias.
// ===========================================================================
__global__ __launch_bounds__(256) void mask_prep_st(const int* __restrict__ mask,
                                                    hbf16* __restrict__ mbias) {
    const int t = blockIdx.x;          // 0..1023
    const int kt = t & 31;
    const int qb = (t >> 5) & 15;
    const int b = t >> 9;
    const int tid = threadIdx.x;
    const int w = tid >> 6;
    const int lane = tid & 63;
    const int quad = lane >> 4;
    const int u = lane & 15;
    const int qrow = qb * 64 + w * 16 + quad * 4;
    const int kcol = kt * 64 + u;
    const int* mp = mask + ((size_t)(b * LQ + qrow)) * LK + kcol;

    bfu8 v0, v1;
#pragma unroll
    for (int ns = 0; ns < 4; ++ns)
#pragma unroll
        for (int rr = 0; rr < 4; ++rr) {
            const int mv = mp[(size_t)rr * LK + ns * 16];
            const __bf16 bias = (mv == 0) ? (__bf16)(-1e9f) : (__bf16)(-10.0f);
            const int j = ns * 4 + rr;
            if (j < 8) v0.b[j] = bias; else v1.b[j - 8] = bias;
        }
    __bf16* dst = (__bf16*)mbias + (size_t)t * 4096 + tid * 16;
    *(bfv8*)dst = v0.v;
    *(bfv8*)(dst + 8) = v1.v;
}

// ===========================================================================
// TIER-A: split-K=2 flash attention, static softmax, UNNORMALIZED partials.
// R12: bare v_exp_f32 via __builtin_amdgcn_exp2f (R11's libm exp2f added
// range-check VALU, regressed). Q pre-scaled by log2e in proj; bias constants
// folded. Mask via packed u16, XCD swizzle, T14 prefetch, setprio.
// ===========================================================================
__global__ __launch_bounds__(256, 4) void attn_split(const hbf16* __restrict__ Qp,
                                                     const hbf16* __restrict__ Kp,
                                                     const hbf16* __restrict__ Vp,
                                                     const unsigned short* __restrict__ mpack,
                                                     float* __restrict__ Opart,
                                                     float* __restrict__ lpart) {
    // bijective XCD swizzle: 1024 blocks = 8 XCDs x 128-chunk; qb fastest.
    const int wg = (blockIdx.x & 7) * 128 + (blockIdx.x >> 3);
    const int qb = wg & 15;
    const int h = (wg >> 4) & 15;
    const int z = wg >> 8;
    const int b = z >> 1;
    const int sp = z & 1;
    const int tid = threadIdx.x;
    const int lane = tid & 63;
    const int w = tid >> 6;
    const int u = lane & 15;
    const int quad = lane >> 4;
    const int qBase = qb * QT;

    __shared__ __align__(16) __bf16 Ks[64 * KS_PITCH];
    __shared__ __align__(16) __bf16 Vt[4672];
    __shared__ __align__(16) __bf16 Ps[4][1184];

    const int qrow_frag = qBase + w * 16 + u;
    const hbf16* qptr = Qp + (size_t)(b * LQ + qrow_frag) * Hdim + h * HDIM + quad * 8;
    const bfv8 af_q0 = *(const bfv8*)qptr;
    const bfv8 af_q1 = *(const bfv8*)(qptr + 32);

    float l_acc[4] = {0.f, 0.f, 0.f, 0.f};
    floatx4 acc_o[4];
#pragma unroll
    for (int nd = 0; nd < 4; ++nd) acc_o[nd] = (floatx4){0.f, 0.f, 0.f, 0.f};

    const int sk = tid >> 2;
    const int sdg = (tid & 3) * 16;
    const int vk2 = (tid >> 3) * 2;
    const int vd0 = (tid & 7) * 8;
    // packed mask: one u16 per thread per tile, fragment-ordered
    const unsigned short* mpk = mpack + (size_t)((b * 16 + qb) * 32) * 256 + tid;

    const int kt0 = sp * (LK / KT / 2);
    const int ktEnd = kt0 + (LK / KT / 2);

    // bias constants pre-multiplied by log2e (S is already scaled by log2e)
    const float BIAS_KEEP = -10.0f * LOG2E;
    const float BIAS_MASK = -1e9f * LOG2E;

    // pending-tile registers (T14 issue-early)
    unsigned int pmw;
    bfu8 pv0, pv1;
    bfv8 pk0, pk1;

#define A_LOADS(kt)                                                            \
    do {                                                                       \
        const int kBase_ = (kt) * KT;                                          \
        pmw = mpk[(size_t)(kt) * 256];                                         \
        const hbf16* vp_ = Vp + (size_t)(b * LK + kBase_ + vk2) * Hdim + h * HDIM + vd0; \
        pv0.v = *(const bfv8*)vp_;                                             \
        pv1.v = *(const bfv8*)(vp_ + Hdim);                                    \
        const hbf16* kp_ = Kp + (size_t)(b * LK + kBase_ + sk) * Hdim + h * HDIM + sdg; \
        pk0 = *(const bfv8*)kp_;                                               \
        pk1 = *(const bfv8*)(kp_ + 8);                                         \
    } while (0)

    A_LOADS(kt0);

    for (int kt = kt0; kt < ktEnd; ++kt) {
        __syncthreads();   // all waves done reading LDS of previous tile
        *(bfv8*)&Ks[sk * KS_PITCH + sdg] = pk0;
        *(bfv8*)&Ks[sk * KS_PITCH + sdg + 8] = pk1;
#pragma unroll
        for (int i = 0; i < 8; ++i) {
            unsigned int pk = (unsigned int)pv0.s[i] | ((unsigned int)pv1.s[i] << 16);
            *(unsigned int*)&Vt[VT_OFF(vd0 + i) + vk2] = pk;
        }
        const unsigned int mw = pmw;   // snapshot current-tile mask word
        __syncthreads();               // LDS tile ready

        // issue next-tile loads NOW; latency hides under QK+softmax+PV
        if (kt + 1 < ktEnd) A_LOADS(kt + 1);

        // S = Q K^T (Q pre-scaled (1/8)*log2e)
        floatx4 acc_s[4];
        __builtin_amdgcn_s_setprio(1);
#pragma unroll
        for (int ns = 0; ns < 4; ++ns) {
            const bfv8 bk0 = *(const bfv8*)&Ks[(ns * 16 + u) * KS_PITCH + quad * 8];
            const bfv8 bk1 = *(const bfv8*)&Ks[(ns * 16 + u) * KS_PITCH + quad * 8 + 32];
            floatx4 a = (floatx4){0.f, 0.f, 0.f, 0.f};
            a = __builtin_amdgcn_mfma_f32_16x16x32_bf16(af_q0, bk0, a, 0, 0, 0);
            a = __builtin_amdgcn_mfma_f32_16x16x32_bf16(af_q1, bk1, a, 0, 0, 0);
            acc_s[ns] = a;
        }
        __builtin_amdgcn_s_setprio(0);

        // static softmax: p = 2^(s + bias2), raw v_exp_f32
        __bf16* Pw = Ps[w];
#pragma unroll
        for (int ns = 0; ns < 4; ++ns)
#pragma unroll
            for (int rr = 0; rr < 4; ++rr) {
                const int j = ns * 4 + rr;
                const float bias = ((mw >> j) & 1u) ? BIAS_KEEP : BIAS_MASK;
                const float p = __builtin_amdgcn_exp2f(acc_s[ns][rr] + bias);
                Pw[PS_OFF(quad * 4 + rr) + ns * 16 + u] = (__bf16)p;
                l_acc[rr] += p;
            }

        // O += P V (same-wave LDS RAW ordered by lgkmcnt)
        const bfv8 af_p0 = *(const bfv8*)&Pw[PS_OFF(u) + quad * 8];
        const bfv8 af_p1 = *(const bfv8*)&Pw[PS_OFF(u) + quad * 8 + 32];
        __builtin_amdgcn_s_setprio(1);
#pragma unroll
        for (int nd = 0; nd < 4; ++nd) {
            const bfv8 bv0 = *(const bfv8*)&Vt[VT_OFF(nd * 16 + u) + quad * 8];
            const bfv8 bv1 = *(const bfv8*)&Vt[VT_OFF(nd * 16 + u) + quad * 8 + 32];
            acc_o[nd] = __builtin_amdgcn_mfma_f32_16x16x32_bf16(af_p0, bv0, acc_o[nd], 0, 0, 0);
            acc_o[nd] = __builtin_amdgcn_mfma_f32_16x16x32_bf16(af_p1, bv1, acc_o[nd], 0, 0, 0);
        }
        __builtin_amdgcn_s_setprio(0);
    }
#undef A_LOADS

    // epilogue: unnormalized O + l partials
#pragma unroll
    for (int rr = 0; rr < 4; ++rr) {
        float l = l_acc[rr];
        l += __shfl_xor(l, 1, 64);
        l += __shfl_xor(l, 2, 64);
        l += __shfl_xor(l, 4, 64);
        l += __shfl_xor(l, 8, 64);
        const int qrow = qBase + w * 16 + quad * 4 + rr;
        const size_t m = (size_t)(b * LQ + qrow);
        float* orow = Opart + (size_t)sp * (BATCH * LQ * Hdim) + m * Hdim + h * HDIM;
#pragma unroll
        for (int nd = 0; nd < 4; ++nd)
            orow[nd * 16 + u] = acc_o[nd][rr];
        if (u == 0)
            lpart[(size_t)sp * (BATCH * LQ * NHEAD) + m * NHEAD + h] = l;
    }
}

// ===========================================================================
// TIER-B attention (R10 proven): single-block-per-(qtile,h,b) static softmax.
// ===========================================================================
__global__ __launch_bounds__(256, 4) void attn_flash_st(const hbf16* __restrict__ Qp,
                                                        const hbf16* __restrict__ Kp,
                                                        const hbf16* __restrict__ Vp,
                                                        const hbf16* __restrict__ mbias,
                                                        hbf16* __restrict__ ctx) {
    const int qb = blockIdx.x;
    const int h = blockIdx.y;
    const int b = blockIdx.z;
    const int tid = threadIdx.x;
    const int lane = tid & 63;
    const int w = tid >> 6;
    const int u = lane & 15;
    const int quad = lane >> 4;
    const int qBase = qb * QT;

    __shared__ __align__(16) __bf16 Ks[64 * KS_PITCH];
    __shared__ __align__(16) __bf16 Vt[4672];
    __shared__ __align__(16) __bf16 Ps[4][1184];

    const int qrow_frag = qBase + w * 16 + u;
    const hbf16* qptr = Qp + (size_t)(b * LQ + qrow_frag) * Hdim + h * HDIM + quad * 8;
    const bfv8 af_q0 = *(const bfv8*)qptr;
    const bfv8 af_q1 = *(const bfv8*)(qptr + 32);

    float l_acc[4] = {0.f, 0.f, 0.f, 0.f};
    floatx4 acc_o[4];
#pragma unroll
    for (int nd = 0; nd < 4; ++nd) acc_o[nd] = (floatx4){0.f, 0.f, 0.f, 0.f};

    const int sk = tid >> 2;
    const int sdg = (tid & 3) * 16;
    const int vk2 = (tid >> 3) * 2;
    const int vd0 = (tid & 7) * 8;
    const __bf16* mbT = (const __bf16*)mbias + (size_t)(b * 16 + qb) * 32 * 4096 + tid * 16;

    for (int kt = 0; kt < LK / KT; ++kt) {
        const int kBase = kt * KT;

        bfu8 mb0, mb1;
        mb0.v = *(const bfv8*)(mbT + (size_t)kt * 4096);
        mb1.v = *(const bfv8*)(mbT + (size_t)kt * 4096 + 8);

        const hbf16* vp0 = Vp + (size_t)(b * LK + kBase + vk2) * Hdim + h * HDIM + vd0;
        bfu8 v0, v1;
        v0.v = *(const bfv8*)vp0;
        v1.v = *(const bfv8*)(vp0 + Hdim);
        const hbf16* kp = Kp + (size_t)(b * LK + kBase + sk) * Hdim + h * HDIM + sdg;
        const bfv8 kv0 = *(const bfv8*)kp;
        const bfv8 kv1 = *(const bfv8*)(kp + 8);

        __syncthreads();
        *(bfv8*)&Ks[sk * KS_PITCH + sdg] = kv0;
        *(bfv8*)&Ks[sk * KS_PITCH + sdg + 8] = kv1;
#pragma unroll
        for (int i = 0; i < 8; ++i) {
            unsigned int pk = (unsigned int)v0.s[i] | ((unsigned int)v1.s[i] << 16);
            *(unsigned int*)&Vt[VT_OFF(vd0 + i) + vk2] = pk;
        }
        __syncthreads();

        floatx4 acc_s[4];
#pragma unroll
        for (int ns = 0; ns < 4; ++ns) {
            const bfv8 bk0 = *(const bfv8*)&Ks[(ns * 16 + u) * KS_PITCH + quad * 8];
            const bfv8 bk1 = *(const bfv8*)&Ks[(ns * 16 + u) * KS_PITCH + quad * 8 + 32];
            floatx4 a = (floatx4){0.f, 0.f, 0.f, 0.f};
            a = __builtin_amdgcn_mfma_f32_16x16x32_bf16(af_q0, bk0, a, 0, 0, 0);
            a = __builtin_amdgcn_mfma_f32_16x16x32_bf16(af_q1, bk1, a, 0, 0, 0);
            acc_s[ns] = a;
        }

        __bf16* Pw = Ps[w];
#pragma unroll
        for (int ns = 0; ns < 4; ++ns)
#pragma unroll
            for (int rr = 0; rr < 4; ++rr) {
                const int j = ns * 4 + rr;
                const float bias = (j < 8) ? (float)mb0.b[j] : (float)mb1.b[j - 8];
                const float p = __expf(acc_s[ns][rr] + bias);
                Pw[PS_OFF(quad * 4 + rr) + ns * 16 + u] = (__bf16)p;
                l_acc[rr] += p;
            }

        const bfv8 af_p0 = *(const bfv8*)&Pw[PS_OFF(u) + quad * 8];
        const bfv8 af_p1 = *(const bfv8*)&Pw[PS_OFF(u) + quad * 8 + 32];
#pragma unroll
        for (int nd = 0; nd < 4; ++nd) {
            const bfv8 bv0 = *(const bfv8*)&Vt[VT_OFF(nd * 16 + u) + quad * 8];
            const bfv8 bv1 = *(const bfv8*)&Vt[VT_OFF(nd * 16 + u) + quad * 8 + 32];
            acc_o[nd] = __builtin_amdgcn_mfma_f32_16x16x32_bf16(af_p0, bv0, acc_o[nd], 0, 0, 0);
            acc_o[nd] = __builtin_amdgcn_mfma_f32_16x16x32_bf16(af_p1, bv1, acc_o[nd], 0, 0, 0);
        }
    }

#pragma unroll
    for (int rr = 0; rr < 4; ++rr) {
        float l = l_acc[rr];
        l += __shfl_xor(l, 1, 64);
        l += __shfl_xor(l, 2, 64);
        l += __shfl_xor(l, 4, 64);
        l += __shfl_xor(l, 8, 64);
        const float invl = 1.0f / l;
        const int qrow = qBase + w * 16 + quad * 4 + rr;
        hbf16* crow = ctx + (size_t)(b * LQ + qrow) * Hdim + h * HDIM;
#pragma unroll
        for (int nd = 0; nd < 4; ++nd)
            crow[nd * 16 + u] = __float2bfloat16(acc_o[nd][rr] * invl);
    }
}

// ===========================================================================
// LayerNorm over last dim (1024), fp32 in d_out, in place.
// ===========================================================================
__global__ __launch_bounds__(256) void ln_kernel(float* __restrict__ x,
                                                 const float* __restrict__ g,
                                                 const float* __restrict__ beta) {
    const int row = blockIdx.x;
    float* xr = x + (size_t)row * Hdim;
    __shared__ float red[256];
    const int tid = threadIdx.x;

    const float4 xi = ((const float4*)xr)[tid];
    red[tid] = xi.x + xi.y + xi.z + xi.w;
    __syncthreads();
    for (int st = 128; st > 0; st >>= 1) {
        if (tid < st) red[tid] += red[tid + st];
        __syncthreads();
    }
    const float mu = red[0] * (1.0f / Hdim);
    __syncthreads();
    {
        float dx = xi.x - mu, dy = xi.y - mu, dz = xi.z - mu, dw = xi.w - mu;
        red[tid] = dx * dx + dy * dy + dz * dz + dw * dw;
    }
    __syncthreads();
    for (int st = 128; st > 0; st >>= 1) {
        if (tid < st) red[tid] += red[tid + st];
        __syncthreads();
    }
    const float rstd = rsqrtf(red[0] * (1.0f / Hdim) + LN_EPS);

    const float4 g4 = ((const float4*)g)[tid];
    const float4 b4 = ((const float4*)beta)[tid];
    float4 y;
    y.x = (xi.x - mu) * rstd * g4.x + b4.x;
    y.y = (xi.y - mu) * rstd * g4.y + b4.y;
    y.z = (xi.z - mu) * rstd * g4.z + b4.z;
    y.w = (xi.w - mu) * rstd * g4.w + b4.w;
    ((float4*)xr)[tid] = y;
}

// ===========================================================================
// Fallback (round-4 proven): fully fused, zero workspace.
// ===========================================================================
__device__ inline float wave_red_sum(float v) {
    v += __shfl_down(v, 32, 64);
    v += __shfl_down(v, 16, 64);
    v += __shfl_down(v, 8, 64);
    v += __shfl_down(v, 4, 64);
    v += __shfl_down(v, 2, 64);
    v += __shfl_down(v, 1, 64);
    return v;
}

__global__ __launch_bounds__(256) void fused_mha(
    const float* __restrict__ q_in, const float* __restrict__ k_in,
    const float* __restrict__ v_in, const int* __restrict__ mask,
    const float* __restrict__ Wq, const float* __restrict__ bq,
    const float* __restrict__ Wk, const float* __restrict__ bk,
    const float* __restrict__ Wv, const float* __restrict__ bv,
    const float* __restrict__ Wo, const float* __restrict__ bo,
    const float* __restrict__ ln_g, const float* __restrict__ ln_b,
    float* __restrict__ out) {
    const int q = blockIdx.x;
    const int b = blockIdx.y;
    const int tid = threadIdx.x;
    const int lane = tid & 63;
    const int w = tid >> 6;

    __shared__ float qrow[Hdim];
    __shared__ float qt[Hdim];
    __shared__ float sc[LK];
    __shared__ float u[Hdim];
    __shared__ float ctxv[Hdim];
    __shared__ float Qh[HDIM];
    __shared__ float red[256];
    __shared__ float sb_sh;

    const float* qp = q_in + (size_t)(b * LQ + q) * Hdim;
    for (int i = tid; i < Hdim; i += 256) qrow[i] = qp[i];
    __syncthreads();

    const float* keyb = k_in + (size_t)b * LK * Hdim;
    const float* valb = v_in + (size_t)b * LK * Hdim;
    const int* mrow = mask + (size_t)(b * LQ + q) * LK;

    for (int h = 0; h < NHEAD; ++h) {
        for (int dd = w; dd < HDIM; dd += 4) {
            const float4* wrow = (const float4*)(Wq + (size_t)(h * HDIM + dd) * Hdim);
            const float4* q4 = (const float4*)qrow;
            float p = 0.f;
#pragma unroll
            for (int i0 = 0; i0 < 4; ++i0) {
                float4 a = wrow[i0 * 64 + lane];
                float4 c = q4[i0 * 64 + lane];
                p += a.x * c.x + a.y * c.y + a.z * c.z + a.w * c.w;
            }
            p = wave_red_sum(p);
            if (lane == 0) Qh[dd] = p + bq[h * HDIM + dd];
        }
        __syncthreads();

        if (tid < HDIM) red[tid] = Qh[tid] * bk[h * HDIM + tid];

        float4 s4 = {0.f, 0.f, 0.f, 0.f};
        for (int d = 0; d < HDIM; ++d) {
            float4 a = ((const float4*)(Wk + (size_t)(h * HDIM + d) * Hdim))[tid];
            float qd = Qh[d];
            s4.x += a.x * qd;
            s4.y += a.y * qd;
            s4.z += a.z * qd;
            s4.w += a.w * qd;
        }
        __syncthreads();
        if (tid == 0) {
            float s = 0.f;
            for (int i = 0; i < HDIM; ++i) s += red[i];
            sb_sh = s;
        }
        ((float4*)qt)[tid] = s4;
        __syncthreads();
        const float sb = sb_sh;

        for (int k = w; k < LK; k += 4) {
            const float4* krow = (const float4*)(keyb + (size_t)k * Hdim);
            const float4* q4 = (const float4*)qt;
            float p = 0.f;
#pragma unroll
            for (int i0 = 0; i0 < 4; ++i0) {
                float4 a = krow[i0 * 64 + lane];
                float4 c = q4[i0 * 64 + lane];
                p += a.x * c.x + a.y * c.y + a.z * c.z + a.w * c.w;
            }
            p = wave_red_sum(p);
            if (lane == 0) {
                float s = (p + sb) * 0.125f;
                if (mrow[k] == 0) s = -1e9f;
                sc[k] = s;
            }
        }
        __syncthreads();

        float m = -1e30f;
        for (int k = tid; k < LK; k += 256) m = fmaxf(m, sc[k]);
        red[tid] = m;
        __syncthreads();
        for (int s = 128; s > 0; s >>= 1) {
            if (tid < s) red[tid] = fmaxf(red[tid], red[tid + s]);
            __syncthreads();
        }
        const float mx = red[0];
        __syncthreads();
        float sum = 0.f;
        for (int k = tid; k < LK; k += 256) {
            float e = __expf(sc[k] - mx);
            sc[k] = e;
            sum += e;
        }
        red[tid] = sum;
        __syncthreads();
        for (int s = 128; s > 0; s >>= 1) {
            if (tid < s) red[tid] += red[tid + s];
            __syncthreads();
        }
        const float inv = 1.0f / red[0];
        for (int k = tid; k < LK; k += 256) sc[k] *= inv;
        __syncthreads();

        {
            float4 acc = {0.f, 0.f, 0.f, 0.f};
            const float4* vb4 = (const float4*)valb;
#pragma unroll 4
            for (int k = 0; k < LK; ++k) {
                float p = sc[k];
                float4 a = vb4[(size_t)k * (Hdim / 4) + tid];
                acc.x += a.x * p;
                acc.y += a.y * p;
                acc.z += a.z * p;
                acc.w += a.w * p;
            }
            ((float4*)u)[tid] = acc;
        }
        __syncthreads();

        for (int dd = w; dd < HDIM; dd += 4) {
            const float4* wrow = (const float4*)(Wv + (size_t)(h * HDIM + dd) * Hdim);
            const float4* u4 = (const float4*)u;
            float p = 0.f;
#pragma unroll
            for (int i0 = 0; i0 < 4; ++i0) {
                float4 a = wrow[i0 * 64 + lane];
                float4 c = u4[i0 * 64 + lane];
                p += a.x * c.x + a.y * c.y + a.z * c.z + a.w * c.w;
            }
            p = wave_red_sum(p);
            if (lane == 0) ctxv[h * HDIM + dd] = p + bv[h * HDIM + dd];
        }
        __syncthreads();
    }

    for (int n = w; n < Hdim; n += 4) {
        const float4* wrow = (const float4*)(Wo + (size_t)n * Hdim);
        const float4* c4 = (const float4*)ctxv;
        float p = 0.f;
#pragma unroll
        for (int i0 = 0; i0 < 4; ++i0) {
            float4 a = wrow[i0 * 64 + lane];
            float4 c = c4[i0 * 64 + lane];
            p += a.x * c.x + a.y * c.y + a.z * c.z + a.w * c.w;
        }
        p = wave_red_sum(p);
        if (lane == 0) qt[n] = p + bo[n] + qrow[n];
    }
    __syncthreads();

    {
        const float4 x4 = ((const float4*)qt)[tid];
        red[tid] = x4.x + x4.y + x4.z + x4.w;
    }
    __syncthreads();
    for (int s = 128; s > 0; s >>= 1) {
        if (tid < s) red[tid] += red[tid + s];
        __syncthreads();
    }
    const float mu = red[0] * (1.0f / Hdim);
    __syncthreads();
    {
        const float4 x4 = ((const float4*)qt)[tid];
        float dx = x4.x - mu, dy = x4.y - mu, dz = x4.z - mu, dw = x4.w - mu;
        red[tid] = dx * dx + dy * dy + dz * dz + dw * dw;
    }
    __syncthreads();
    for (int s = 128; s > 0; s >>= 1) {
        if (tid < s) red[tid] += red[tid + s];
        __syncthreads();
    }
    const float rstd = rsqrtf(red[0] * (1.0f / Hdim) + LN_EPS);

    float* orow = out + (size_t)(b * LQ + q) * Hdim;
    const float4 x4 = ((const float4*)qt)[tid];
    const float4 g4 = ((const float4*)ln_g)[tid];
    const float4 b4 = ((const float4*)ln_b)[tid];
    float4 y;
    y.x = (x4.x - mu) * rstd * g4.x + b4.x;
    y.y = (x4.y - mu) * rstd * g4.y + b4.y;
    y.z = (x4.z - mu) * rstd * g4.z + b4.z;
    y.w = (x4.w - mu) * rstd * g4.w + b4.w;
    ((float4*)orow)[tid] = y;
}

extern "C" void kernel_launch(void* const* d_in, const int* in_sizes, int n_in,
                              void* d_out, int out_size, void* d_ws, size_t ws_size,
                              hipStream_t stream) {
    const float* query = (const float*)d_in[0];
    const float* key   = (const float*)d_in[1];
    const float* value = (const float*)d_in[2];
    const int*   mask  = (const int*)d_in[3];
    const float* Wq = (const float*)d_in[4];
    const float* bq = (const float*)d_in[5];
    const float* Wk = (const float*)d_in[6];
    const float* bk = (const float*)d_in[7];
    const float* Wv = (const float*)d_in[8];
    const float* bv = (const float*)d_in[9];
    const float* Wo = (const float*)d_in[10];
    const float* bo = (const float*)d_in[11];
    const float* ln_g = (const float*)d_in[12];
    const float* ln_b = (const float*)d_in[13];
    float* out = (float*)d_out;

    const size_t MB = 1024 * 1024;
    dim3 blk(256);

    if (ws_size >= 50 * MB) {
        // TIER-A (5 kernels): cvt+maskpack -> proj(1D XCD grid) -> attn(raw exp2)
        //                     -> merge+ctxGEMM -> ln
        // Persistent: Qp@0(4) Kp@4(8) Vp@12(8) Opart@20(16) mpack@46(1) lpart@47(1)
        // cvt scratch (dead before Opart written; disjoint from mpack):
        //   qb@20(4) kb@24(8) vb@32(8) Wqb@40(2) Wkb@42(2) Wvb@44(2)  -> 20..46
        char* p = (char*)d_ws;
        hbf16* Qp    = (hbf16*)(p + 0 * MB);
        hbf16* Kp    = (hbf16*)(p + 4 * MB);
        hbf16* Vp    = (hbf16*)(p + 12 * MB);
        float* Opart = (float*)(p + 20 * MB);
        unsigned short* mpack = (unsigned short*)(p + 46 * MB);
        float* lpart = (float*)(p + 47 * MB);

        hbf16* qb  = (hbf16*)(p + 20 * MB);
        hbf16* kb  = (hbf16*)(p + 24 * MB);
        hbf16* vb  = (hbf16*)(p + 32 * MB);
        hbf16* Wqb = (hbf16*)(p + 40 * MB);
        hbf16* Wkb = (hbf16*)(p + 42 * MB);
        hbf16* Wvb = (hbf16*)(p + 44 * MB);

        cvt_all<<<dim3(7680), blk, 0, stream>>>(query, key, value, Wq, Wk, Wv,
                                                mask, qb, kb, vb, Wqb, Wkb, Wvb,
                                                mpack);
        proj3_glds<<<dim3(640), blk, 0, stream>>>(
            qb, kb, vb, Wqb, Wkb, Wvb, bq, bk, bv, Qp, Kp, Vp);

        attn_split<<<dim3(1024), blk, 0, stream>>>(
            Qp, Kp, Vp, mpack, Opart, lpart);

        gemm_ctx_merge<<<dim3(Hdim / 64, (BATCH * LQ) / 64), blk, 0, stream>>>(
            Opart, lpart, Wo, bo, query, out);
        ln_kernel<<<BATCH * LQ, blk, 0, stream>>>(out, ln_g, ln_b);
    } else if (ws_size >= 32 * MB) {
        // TIER-B: exact round-10 proven path
        char* p = (char*)d_ws;
        hbf16* Qp = (hbf16*)p;    p += 4 * MB;
        hbf16* Kp = (hbf16*)p;    p += 8 * MB;
        hbf16* Vp = (hbf16*)p;    p += 8 * MB;
        hbf16* ctxb = (hbf16*)p;  p += 4 * MB;
        hbf16* mbias = (hbf16*)p; p += 8 * MB;

        gemm_mfma_f32<<<dim3(Hdim / 64, (BATCH * LQ) / 64), blk, 0, stream>>>(query, Wq, bq, Qp, 0.125f);
        gemm_mfma_f32<<<dim3(Hdim / 64, (BATCH * LK) / 64), blk, 0, stream>>>(key, Wk, bk, Kp, 1.0f);
        gemm_mfma_f32<<<dim3(Hdim / 64, (BATCH * LK) / 64), blk, 0, stream>>>(value, Wv, bv, Vp, 1.0f);
        mask_prep_st<<<dim3(1024), blk, 0, stream>>>(mask, mbias);
        attn_flash_st<<<dim3(LQ / QT, NHEAD, BATCH), blk, 0, stream>>>(Qp, Kp, Vp, mbias, ctxb);
        gemm_mfma_ctx<<<dim3(Hdim / 64, (BATCH * LQ) / 64), blk, 0, stream>>>(ctxb, Wo, bo, query, out);
        ln_kernel<<<BATCH * LQ, blk, 0, stream>>>(out, ln_g, ln_b);
    } else {
        fused_mha<<<dim3(LQ, BATCH), dim3(256), 0, stream>>>(
            query, key, value, mask, Wq, bq, Wk, bk, Wv, bv, Wo, bo, ln_g, ln_b, out);
    }
}